// Round 7
// baseline (1010.120 us; speedup 1.0000x reference)
//
#include <hip/hip_runtime.h>
#include <math.h>

#define NT 262144
#define NS 512
#define ES 2097152
#define EO 8192
#define NLAYER 4
#define RCAP 512        // per-wave record stage (mean 128, +34 sigma)
#define EPB 4096        // edges per scatter/hist block-chunk

typedef short bf16x8 __attribute__((ext_vector_type(8)));
typedef float f32x16 __attribute__((ext_vector_type(16)));

__device__ inline unsigned short rne_bf16(float f) {
    unsigned int u = __float_as_uint(f);
    u += 0x7FFF + ((u >> 16) & 1);
    return (unsigned short)(u >> 16);
}

// ---------------- per-node CSR build, XCD-partitioned ----------------
__global__ void hist_xcd_kernel(const int* __restrict__ dst, int* __restrict__ deg) {
    int p = blockIdx.x;
    int g = p & 7;
    int base = (p >> 3) * EPB;
    for (int i = threadIdx.x; i < EPB; i += 256) {
        int d = dst[base + i];
        if (((d >> 9) & 7) == g) atomicAdd(&deg[d], 1);
    }
}

__global__ void scan1_kernel(const int* __restrict__ deg, int* __restrict__ rowptr,
                             int* __restrict__ bsum) {
    __shared__ int lds[1024];
    int t = threadIdx.x;
    int g = blockIdx.x * 1024 + t;
    int v = deg[g];
    lds[t] = v;
    __syncthreads();
    for (int off = 1; off < 1024; off <<= 1) {
        int x = (t >= off) ? lds[t - off] : 0;
        __syncthreads();
        lds[t] += x;
        __syncthreads();
    }
    rowptr[g] = lds[t] - v;
    if (t == 1023) bsum[blockIdx.x] = lds[t];
}

__global__ void scan2_kernel(int* bsum) {
    __shared__ int lds[256];
    int t = threadIdx.x;
    int v = bsum[t];
    lds[t] = v;
    __syncthreads();
    for (int off = 1; off < 256; off <<= 1) {
        int x = (t >= off) ? lds[t - off] : 0;
        __syncthreads();
        lds[t] += x;
        __syncthreads();
    }
    bsum[t] = lds[t] - v;
}

__global__ void scan3_kernel(int* __restrict__ rowptr, const int* __restrict__ bsum,
                             int* __restrict__ cursor) {
    int t = threadIdx.x;
    int g = blockIdx.x * 1024 + t;
    int v = rowptr[g] + bsum[blockIdx.x];
    rowptr[g] = v;
    cursor[g] = v;
    if (g == NT - 1) rowptr[NT] = ES;
}

__global__ void scatter_xcd_kernel(const int* __restrict__ ei, int* __restrict__ cur,
                                   unsigned short* __restrict__ ebuf) {
    int p = blockIdx.x;
    int g = p & 7;
    int base = (p >> 3) * EPB;
    for (int i = threadIdx.x; i < EPB; i += 256) {
        int d = ei[ES + base + i];
        if (((d >> 9) & 7) == g) {
            int s = ei[base + i];
            int pos = atomicAdd(&cur[d], 1);
            ebuf[pos] = (unsigned short)((s & 511) | ((d & 63) << 9));
        }
    }
}

// ---------------- CSR build (small graph, single block) ----------------
__global__ void small_csr_kernel(const int* __restrict__ oei, int* __restrict__ rowptrS,
                                 int* __restrict__ srcsS) {
    __shared__ int sdeg[NS];
    __shared__ int scur[NS];
    int t = threadIdx.x;
    if (t < NS) sdeg[t] = 0;
    __syncthreads();
    for (int e = t; e < EO; e += 1024) atomicAdd(&sdeg[oei[EO + e]], 1);
    __syncthreads();
    int myv = (t < NS) ? sdeg[t] : 0;
    __syncthreads();
    for (int off = 1; off < NS; off <<= 1) {
        int x = (t >= off && t < NS) ? sdeg[t - off] : 0;
        __syncthreads();
        if (t < NS) sdeg[t] += x;
        __syncthreads();
    }
    if (t < NS) {
        int excl = sdeg[t] - myv;
        rowptrS[t] = excl;
        scur[t] = excl;
        if (t == 0) rowptrS[NS] = EO;
    }
    __syncthreads();
    for (int e = t; e < EO; e += 1024) {
        int d = oei[EO + e];
        int pos = atomicAdd(&scur[d], 1);
        srcsS[pos] = oei[e];
    }
}

// ---------------- MFMA gconv: quarter-wave float4 gather ----------------
// Block = one 64-node tile (XCD swizzle: subgraph's 8 tiles on one XCD; gather
// L2-resident — verified R3). Wave w owns rows [w*16,w*16+16). Each 16-lane
// QUARTER owns 4 rows and streams its dst-grouped records: one
// global_load_dwordx4 covers 4 edges/wave-instr (lane = 4 cols), run-
// accumulated in a float4 register, flushed via ds_write_b128 on row change.
__global__ __launch_bounds__(256, 6) void gconv_mfma_kernel(
    const float* __restrict__ hin, const int* __restrict__ rowptr,
    const unsigned short* __restrict__ ebuf,
    const float* __restrict__ Wr, const float* __restrict__ Wt, const float* __restrict__ br,
    float* __restrict__ hout, float* __restrict__ stats)
{
    __shared__ float agg[64 * 68];                 // 17.4 KB
    __shared__ unsigned short erec[4 * RCAP];      // 4 KB

    int p = blockIdx.x;
    int xx = p & 7;
    int q = p >> 3;
    int sub = xx + 8 * (q >> 3);
    int tile = q & 7;
    int nb = (sub * 8 + tile) * 64;

    int tid = threadIdx.x;
    int w = tid >> 6;
    int l = tid & 63;

    for (int i = tid; i < 64 * 68 / 4; i += 256) ((float4*)agg)[i] = make_float4(0.f, 0.f, 0.f, 0.f);
    __syncthreads();

    // ---- gather ----
    int row0 = w * 16;                 // block-local first row of wave
    int qtr = l >> 4;                  // quarter 0..3
    int c4 = (l & 15) * 4;             // column base
    int r4 = row0 + qtr * 4;           // quarter's first block-local row
    int q0 = rowptr[nb + row0];        // wave range (uniform)
    int q1 = rowptr[nb + row0 + 16];
    int e0 = rowptr[nb + r4];          // quarter range
    int e1 = rowptr[nb + r4 + 4];

    const float* hsub = hin + (size_t)sub * 512 * 64;
    unsigned short* myrec = erec + w * RCAP;
    for (int i = l; i < q1 - q0; i += 64) myrec[i] = ebuf[q0 + i];
    __builtin_amdgcn_wave_barrier();

    int pos = e0 - q0;
    int pend = e1 - q0;
    float4 accv = make_float4(0.f, 0.f, 0.f, 0.f);
    int cur = r4;
    while (__ballot(pos < pend)) {
        bool active = pos < pend;
        int rp = active ? pos : 0;
        unsigned rec = myrec[rp];                       // ds_read_u16 (quarter-bcast)
        int d = rec >> 9;
        const float* srcp = hsub + (rec & 511) * 64 + c4;
        float4 v = *(const float4*)srcp;                // always in-bounds
        if (active) {
            if (d != cur) {
                *(float4*)(agg + cur * 68 + c4) = accv;
                accv = make_float4(0.f, 0.f, 0.f, 0.f);
                cur = d;
            }
            accv.x += v.x; accv.y += v.y; accv.z += v.z; accv.w += v.w;
            pos++;
        }
    }
    *(float4*)(agg + cur * 68 + c4) = accv;   // final flush (untouched rows stay 0)

    // ---- B fragments ----
    int nt = w >> 1;
    int ct = w & 1;
    int n_out = ct * 32 + (l & 31);
    int kh = l >> 5;

    bf16x8 Bh[8], Bl[8];
    #pragma unroll
    for (int kc = 0; kc < 8; kc++) {
        int kbase = kc * 16 + kh * 8;
        const float* wsrc = (kbase < 64) ? (Wr + n_out * 64 + kbase)
                                         : (Wt + n_out * 64 + (kbase - 64));
        float4 u0 = *(const float4*)(wsrc);
        float4 u1 = *(const float4*)(wsrc + 4);
        float vv[8] = {u0.x, u0.y, u0.z, u0.w, u1.x, u1.y, u1.z, u1.w};
        #pragma unroll
        for (int j = 0; j < 8; j++) {
            unsigned short hi = rne_bf16(vv[j]);
            float hif = __uint_as_float((unsigned int)hi << 16);
            Bh[kc][j] = (short)hi;
            Bl[kc][j] = (short)rne_bf16(vv[j] - hif);
        }
    }
    float bias = br[n_out];
    __syncthreads();

    // ---- MFMA: A = [agg | h], split-bf16 (hh, lh, hl) ----
    f32x16 acc;
    #pragma unroll
    for (int j = 0; j < 16; j++) acc[j] = bias;

    int row = nt * 32 + (l & 31);
    const float* hrow = hin + (size_t)(nb + row) * 64;
    #pragma unroll
    for (int kc = 0; kc < 8; kc++) {
        int k0 = kc * 16 + kh * 8;
        float vv[8];
        if (kc < 4) {
            float4 a0 = *(const float4*)(agg + row * 68 + k0);
            float4 a1 = *(const float4*)(agg + row * 68 + k0 + 4);
            vv[0]=a0.x; vv[1]=a0.y; vv[2]=a0.z; vv[3]=a0.w;
            vv[4]=a1.x; vv[5]=a1.y; vv[6]=a1.z; vv[7]=a1.w;
        } else {
            float4 a0 = *(const float4*)(hrow + k0 - 64);
            float4 a1 = *(const float4*)(hrow + k0 - 60);
            vv[0]=a0.x; vv[1]=a0.y; vv[2]=a0.z; vv[3]=a0.w;
            vv[4]=a1.x; vv[5]=a1.y; vv[6]=a1.z; vv[7]=a1.w;
        }
        bf16x8 ah, al;
        #pragma unroll
        for (int j = 0; j < 8; j++) {
            unsigned short hi = rne_bf16(vv[j]);
            float hif = __uint_as_float((unsigned int)hi << 16);
            ah[j] = (short)hi;
            al[j] = (short)rne_bf16(vv[j] - hif);
        }
        acc = __builtin_amdgcn_mfma_f32_32x32x16_bf16(ah, Bh[kc], acc, 0, 0, 0);
        acc = __builtin_amdgcn_mfma_f32_32x32x16_bf16(al, Bh[kc], acc, 0, 0, 0);
        acc = __builtin_amdgcn_mfma_f32_32x32x16_bf16(ah, Bl[kc], acc, 0, 0, 0);
    }

    // ---- epilogue: store h1 + BN stats ----
    float s = 0.f, qv = 0.f;
    #pragma unroll
    for (int j = 0; j < 16; j++) {
        int crow = (j & 3) + 8 * (j >> 2) + 4 * (l >> 5);
        int node = nb + nt * 32 + crow;
        float v = acc[j];
        hout[node * 64 + n_out] = v;
        s += v;
        qv += v * v;
    }
    s += __shfl_xor(s, 32, 64);
    qv += __shfl_xor(qv, 32, 64);
    int rep = p & 31;
    if ((l & 32) == 0) {
        atomicAdd(&stats[rep * 128 + n_out], s);
        atomicAdd(&stats[rep * 128 + 64 + n_out], qv);
    }
}

// ---------------- VALU gconv (512-node small graph) ----------
__global__ __launch_bounds__(512, 6) void gconv_kernel(
    const float* __restrict__ hin, const int* __restrict__ rowptr, const int* __restrict__ srcs,
    const float* __restrict__ Wr, const float* __restrict__ Wt, const float* __restrict__ br,
    float* __restrict__ hout, float* __restrict__ stats)
{
    __shared__ float wrt[4096];
    __shared__ float wtt[4096];
    __shared__ float4 aggT[8][64];
    __shared__ float4 hT[8][64];
    __shared__ float sbuf[8][64];
    __shared__ float qbuf[8][64];
    __shared__ float brs[64];

    int tid = threadIdx.x;
    for (int idx = tid; idx < 4096; idx += 512) {
        int cc = idx >> 6, kk = idx & 63;
        wrt[kk * 64 + ((kk + cc) & 63)] = Wr[idx];
        wtt[kk * 64 + ((kk + cc) & 63)] = Wt[idx];
    }
    if (tid < 64) brs[tid] = br[tid];
    __syncthreads();

    int w = tid >> 6;
    int c = tid & 63;
    int node0 = (blockIdx.x * 8 + w) * 4;

    float* aggp = (float*)&aggT[w][0];
    float* hp   = (float*)&hT[w][0];
    #pragma unroll
    for (int r = 0; r < 4; r++) {
        int node = node0 + r;
        hp[c * 4 + r] = hin[node * 64 + c];
        int e0 = rowptr[node], e1 = rowptr[node + 1];
        float a = 0.f;
        int e = e0;
        for (; e + 4 <= e1; e += 4) {
            int s0 = srcs[e], s1 = srcs[e + 1], s2 = srcs[e + 2], s3 = srcs[e + 3];
            float v0 = hin[s0 * 64 + c];
            float v1 = hin[s1 * 64 + c];
            float v2 = hin[s2 * 64 + c];
            float v3 = hin[s3 * 64 + c];
            a += (v0 + v1) + (v2 + v3);
        }
        for (; e < e1; e++) a += hin[srcs[e] * 64 + c];
        aggp[c * 4 + r] = a;
    }

    float o0 = brs[c], o1 = o0, o2 = o0, o3 = o0;
    #pragma unroll 8
    for (int k = 0; k < 64; k++) {
        float wr = wrt[k * 64 + ((k + c) & 63)];
        float wt = wtt[k * 64 + ((k + c) & 63)];
        float4 av = aggT[w][k];
        float4 hv = hT[w][k];
        o0 += wr * av.x + wt * hv.x;
        o1 += wr * av.y + wt * hv.y;
        o2 += wr * av.z + wt * hv.z;
        o3 += wr * av.w + wt * hv.w;
    }
    hout[(node0 + 0) * 64 + c] = o0;
    hout[(node0 + 1) * 64 + c] = o1;
    hout[(node0 + 2) * 64 + c] = o2;
    hout[(node0 + 3) * 64 + c] = o3;

    sbuf[w][c] = (o0 + o1) + (o2 + o3);
    qbuf[w][c] = (o0 * o0 + o1 * o1) + (o2 * o2 + o3 * o3);
    __syncthreads();
    int rep = blockIdx.x & 31;
    if (w == 0) {
        float s = 0.f;
        #pragma unroll
        for (int ww = 0; ww < 8; ww++) s += sbuf[ww][c];
        atomicAdd(&stats[rep * 128 + c], s);
    } else if (w == 1) {
        float q = 0.f;
        #pragma unroll
        for (int ww = 0; ww < 8; ww++) q += qbuf[ww][c];
        atomicAdd(&stats[rep * 128 + 64 + c], q);
    }
}

// ---------------- subgraph mean (only for the initial x) ----------------
__global__ void smean_kernel(const float* __restrict__ hin, float* __restrict__ xsum) {
    __shared__ float red[16][64];
    int t = threadIdx.x;
    int w = t >> 6, c = t & 63;
    int n = blockIdx.x;
    int base = n * 64 + c;
    float s = 0.f;
    #pragma unroll 8
    for (int j = 0; j < 32; j++) {
        int si = w * 32 + j;
        s += hin[si * 32768 + base];
    }
    red[w][c] = s;
    __syncthreads();
    if (w == 0) {
        float tot = 0.f;
        #pragma unroll
        for (int ww = 0; ww < 16; ww++) tot += red[ww][c];
        xsum[base] = tot * (1.f / 512.f);
    }
}

// ---- h = relu(bn(h1)+bn(h2)[n]) + next-layer smean, BN-finalize fused ----
__global__ __launch_bounds__(1024) void combine_smean_kernel(
    const float* __restrict__ h1, const float* __restrict__ h2,
    const float* __restrict__ stB, const float* __restrict__ stS,
    const float* __restrict__ gB, const float* __restrict__ bB,
    const float* __restrict__ gS, const float* __restrict__ bS,
    float* __restrict__ hout, float* __restrict__ xsum)
{
    __shared__ float bnp[256];
    __shared__ float red[16][64];
    int t = threadIdx.x;
    if (t < 64) {
        int c = t;
        float sb = 0.f, qb = 0.f, ss = 0.f, qs = 0.f;
        for (int r2 = 0; r2 < 32; r2++) {
            sb += stB[r2 * 128 + c];
            qb += stB[r2 * 128 + 64 + c];
            ss += stS[r2 * 128 + c];
            qs += stS[r2 * 128 + 64 + c];
        }
        float muB = sb * (1.f / 262144.f);
        float varB = qb * (1.f / 262144.f) - muB * muB;
        float scB = gB[c] * rsqrtf(varB + 1e-5f);
        bnp[c] = scB;
        bnp[64 + c] = bB[c] - muB * scB;
        float muS = ss * (1.f / 512.f);
        float varS = qs * (1.f / 512.f) - muS * muS;
        float scS = gS[c] * rsqrtf(varS + 1e-5f);
        bnp[128 + c] = scS;
        bnp[192 + c] = bS[c] - muS * scS;
    }
    __syncthreads();

    int w = t >> 6;
    int l = t & 63;
    int c4 = (l & 15) * 4;
    int r = l >> 4;
    int n = blockIdx.x;

    float4 sB = *(const float4*)(bnp + c4);
    float4 hB = *(const float4*)(bnp + 64 + c4);
    float4 sS = *(const float4*)(bnp + 128 + c4);
    float4 hS = *(const float4*)(bnp + 192 + c4);
    float4 b2 = *(const float4*)(h2 + n * 64 + c4);
    float bx = b2.x * sS.x + hS.x;
    float by = b2.y * sS.y + hS.y;
    float bz = b2.z * sS.z + hS.z;
    float bw = b2.w * sS.w + hS.w;

    float4 acc = make_float4(0.f, 0.f, 0.f, 0.f);
    #pragma unroll
    for (int j = 0; j < 8; j++) {
        int si = w * 32 + j * 4 + r;
        size_t base = (size_t)(si * 512 + n) * 64 + c4;
        float4 a = *(const float4*)(h1 + base);
        float4 v;
        v.x = fmaxf(a.x * sB.x + hB.x + bx, 0.f);
        v.y = fmaxf(a.y * sB.y + hB.y + by, 0.f);
        v.z = fmaxf(a.z * sB.z + hB.z + bz, 0.f);
        v.w = fmaxf(a.w * sB.w + hB.w + bw, 0.f);
        *(float4*)(hout + base) = v;
        acc.x += v.x; acc.y += v.y; acc.z += v.z; acc.w += v.w;
    }
    acc.x += __shfl_xor(acc.x, 16, 64); acc.y += __shfl_xor(acc.y, 16, 64);
    acc.z += __shfl_xor(acc.z, 16, 64); acc.w += __shfl_xor(acc.w, 16, 64);
    acc.x += __shfl_xor(acc.x, 32, 64); acc.y += __shfl_xor(acc.y, 32, 64);
    acc.z += __shfl_xor(acc.z, 32, 64); acc.w += __shfl_xor(acc.w, 32, 64);
    if (l < 16) {
        red[w][c4 + 0] = acc.x;
        red[w][c4 + 1] = acc.y;
        red[w][c4 + 2] = acc.z;
        red[w][c4 + 3] = acc.w;
    }
    __syncthreads();
    if (t < 64) {
        float tot = 0.f;
        #pragma unroll
        for (int ww = 0; ww < 16; ww++) tot += red[ww][t];
        xsum[n * 64 + t] = tot * (1.f / 512.f);
    }
}

// ---------------- head ----------------
__global__ void head_kernel(const float* __restrict__ xs, const float* __restrict__ W1,
                            const float* __restrict__ b1, const float* __restrict__ W2,
                            const float* __restrict__ b2, float* __restrict__ out) {
    __shared__ float z[64];
    __shared__ float hid[128];
    int t = threadIdx.x;
    int n = blockIdx.x;
    if (t < 64) {
        float v = xs[n * 64 + t];
        float m = v;
        for (int off = 32; off >= 1; off >>= 1) m = fmaxf(m, __shfl_xor(m, off, 64));
        float e = expf(v - m);
        float s = e;
        for (int off = 32; off >= 1; off >>= 1) s += __shfl_xor(s, off, 64);
        z[t] = v - m - logf(s);
    }
    __syncthreads();
    {
        float acc = b1[t];
        const float* wrow = W1 + t * 64;
        #pragma unroll 8
        for (int k = 0; k < 64; k++) acc += z[k] * wrow[k];
        hid[t] = fmaxf(acc, 0.f);
    }
    __syncthreads();
    if (t < 10) {
        float o = b2[t];
        const float* wrow = W2 + t * 128;
        #pragma unroll 8
        for (int j = 0; j < 128; j++) o += hid[j] * wrow[j];
        out[n * 10 + t] = o;
    }
}

extern "C" void kernel_launch(void* const* d_in, const int* in_sizes, int n_in,
                              void* d_out, int out_size, void* d_ws, size_t ws_size,
                              hipStream_t stream) {
    const float* x       = (const float*)d_in[0];
    const float* Wrel    = (const float*)d_in[1];
    const float* brel    = (const float*)d_in[2];
    const float* Wroot   = (const float*)d_in[3];
    const float* bn_g    = (const float*)d_in[4];
    const float* bn_b    = (const float*)d_in[5];
    const float* Wrel_s  = (const float*)d_in[6];
    const float* brel_s  = (const float*)d_in[7];
    const float* Wroot_s = (const float*)d_in[8];
    const float* bns_g   = (const float*)d_in[9];
    const float* bns_b   = (const float*)d_in[10];
    const float* W1      = (const float*)d_in[11];
    const float* b1      = (const float*)d_in[12];
    const float* W2      = (const float*)d_in[13];
    const float* b2      = (const float*)d_in[14];
    const int* ei        = (const int*)d_in[15];
    const int* oei       = (const int*)d_in[16];
    float* out = (float*)d_out;

    char* ws = (char*)d_ws;
    size_t off = 0;
    auto alloc = [&](size_t bytes) -> void* {
        void* p = ws + off;
        off = (off + bytes + 255) & ~(size_t)255;
        return p;
    };
    float* h     = (float*)alloc((size_t)NT * 64 * 4);
    float* h1    = (float*)alloc((size_t)NT * 64 * 4);
    float* xsum  = (float*)alloc(NS * 64 * 4);
    float* h2    = (float*)alloc(NS * 64 * 4);
    float* stats = (float*)alloc(NLAYER * 2 * 4096 * 4);
    int* deg     = (int*)alloc((size_t)NT * 4);
    int* rowptr  = (int*)alloc((size_t)(NT + 1) * 4);
    int* cursor  = (int*)alloc((size_t)NT * 4);
    int* bsum    = (int*)alloc(256 * 4);
    unsigned short* ebuf = (unsigned short*)alloc((size_t)ES * 2);
    int* rowptrS = (int*)alloc(513 * 4);
    int* srcsS   = (int*)alloc(EO * 4);
    (void)ws_size; (void)in_sizes; (void)n_in; (void)out_size;

    hipMemsetAsync(deg, 0, (size_t)NT * 4, stream);
    hipMemsetAsync(stats, 0, (size_t)NLAYER * 2 * 4096 * 4, stream);

    hist_xcd_kernel<<<ES / EPB * 8, 256, 0, stream>>>(ei + ES, deg);
    scan1_kernel<<<NT / 1024, 1024, 0, stream>>>(deg, rowptr, bsum);
    scan2_kernel<<<1, 256, 0, stream>>>(bsum);
    scan3_kernel<<<NT / 1024, 1024, 0, stream>>>(rowptr, bsum, cursor);
    scatter_xcd_kernel<<<ES / EPB * 8, 256, 0, stream>>>(ei, cursor, ebuf);
    small_csr_kernel<<<1, 1024, 0, stream>>>(oei, rowptrS, srcsS);

    smean_kernel<<<NS, 1024, 0, stream>>>(x, xsum);   // xsum of layer-0 input

    for (int i = 0; i < NLAYER; i++) {
        const float* hin = (i == 0) ? x : h;
        float* stB = stats + i * 8192;
        float* stS = stB + 4096;
        gconv_mfma_kernel<<<NT / 64, 256, 0, stream>>>(hin, rowptr, ebuf,
            Wrel + i * 4096, Wroot + i * 4096, brel + i * 64, h1, stB);
        gconv_kernel<<<NS / 32, 512, 0, stream>>>(xsum, rowptrS, srcsS,
            Wrel_s + i * 4096, Wroot_s + i * 4096, brel_s + i * 64, h2, stS);
        combine_smean_kernel<<<NS, 1024, 0, stream>>>(h1, h2, stB, stS,
            bn_g + i * 64, bn_b + i * 64, bns_g + i * 64, bns_b + i * 64, h, xsum);
    }
    head_kernel<<<NS, 128, 0, stream>>>(xsum, W1, b1, W2, b2, out);
}

// Round 8
// 935.987 us; speedup vs baseline: 1.0792x; 1.0792x over previous
//
#include <hip/hip_runtime.h>
#include <math.h>

#define NT 262144
#define NS 512
#define ES 2097152
#define EO 8192
#define NLAYER 4
#define RCAP 512        // per-wave record stage (mean 128, +34 sigma)
#define EPB 4096        // edges per scatter/hist block-chunk

typedef short bf16x8 __attribute__((ext_vector_type(8)));
typedef float f32x16 __attribute__((ext_vector_type(16)));

__device__ inline unsigned short rne_bf16(float f) {
    unsigned int u = __float_as_uint(f);
    u += 0x7FFF + ((u >> 16) & 1);
    return (unsigned short)(u >> 16);
}

// ---------------- per-node CSR build, XCD-partitioned ----------------
__global__ void hist_xcd_kernel(const int* __restrict__ dst, int* __restrict__ deg) {
    int p = blockIdx.x;
    int g = p & 7;
    int base = (p >> 3) * EPB;
    for (int i = threadIdx.x; i < EPB; i += 256) {
        int d = dst[base + i];
        if (((d >> 9) & 7) == g) atomicAdd(&deg[d], 1);
    }
}

__global__ void scan1_kernel(const int* __restrict__ deg, int* __restrict__ rowptr,
                             int* __restrict__ bsum) {
    __shared__ int lds[1024];
    int t = threadIdx.x;
    int g = blockIdx.x * 1024 + t;
    int v = deg[g];
    lds[t] = v;
    __syncthreads();
    for (int off = 1; off < 1024; off <<= 1) {
        int x = (t >= off) ? lds[t - off] : 0;
        __syncthreads();
        lds[t] += x;
        __syncthreads();
    }
    rowptr[g] = lds[t] - v;
    if (t == 1023) bsum[blockIdx.x] = lds[t];
}

__global__ void scan2_kernel(int* bsum) {
    __shared__ int lds[256];
    int t = threadIdx.x;
    int v = bsum[t];
    lds[t] = v;
    __syncthreads();
    for (int off = 1; off < 256; off <<= 1) {
        int x = (t >= off) ? lds[t - off] : 0;
        __syncthreads();
        lds[t] += x;
        __syncthreads();
    }
    bsum[t] = lds[t] - v;
}

__global__ void scan3_kernel(int* __restrict__ rowptr, const int* __restrict__ bsum,
                             int* __restrict__ cursor) {
    int t = threadIdx.x;
    int g = blockIdx.x * 1024 + t;
    int v = rowptr[g] + bsum[blockIdx.x];
    rowptr[g] = v;
    cursor[g] = v;
    if (g == NT - 1) rowptr[NT] = ES;
}

__global__ void scatter_xcd_kernel(const int* __restrict__ ei, int* __restrict__ cur,
                                   unsigned short* __restrict__ ebuf) {
    int p = blockIdx.x;
    int g = p & 7;
    int base = (p >> 3) * EPB;
    for (int i = threadIdx.x; i < EPB; i += 256) {
        int d = ei[ES + base + i];
        if (((d >> 9) & 7) == g) {
            int s = ei[base + i];
            int pos = atomicAdd(&cur[d], 1);
            ebuf[pos] = (unsigned short)((s & 511) | ((d & 63) << 9));
        }
    }
}

// ---------------- CSR build (small graph, single block) ----------------
__global__ void small_csr_kernel(const int* __restrict__ oei, int* __restrict__ rowptrS,
                                 int* __restrict__ srcsS) {
    __shared__ int sdeg[NS];
    __shared__ int scur[NS];
    int t = threadIdx.x;
    if (t < NS) sdeg[t] = 0;
    __syncthreads();
    for (int e = t; e < EO; e += 1024) atomicAdd(&sdeg[oei[EO + e]], 1);
    __syncthreads();
    int myv = (t < NS) ? sdeg[t] : 0;
    __syncthreads();
    for (int off = 1; off < NS; off <<= 1) {
        int x = (t >= off && t < NS) ? sdeg[t - off] : 0;
        __syncthreads();
        if (t < NS) sdeg[t] += x;
        __syncthreads();
    }
    if (t < NS) {
        int excl = sdeg[t] - myv;
        rowptrS[t] = excl;
        scur[t] = excl;
        if (t == 0) rowptrS[NS] = EO;
    }
    __syncthreads();
    for (int e = t; e < EO; e += 1024) {
        int d = oei[EO + e];
        int pos = atomicAdd(&scur[d], 1);
        srcsS[pos] = oei[e];
    }
}

// ---------------- MFMA gconv: quarter-wave float4 gather ----------------
// Block = one 64-node tile (XCD swizzle: subgraph's 8 tiles on one XCD; gather
// L2-resident — verified R3). Wave w owns rows [w*16,w*16+16). Each 16-lane
// QUARTER owns 4 rows and streams its dst-grouped records: one
// global_load_dwordx4 covers 4 edges/wave-instr (lane = 4 cols), run-
// accumulated in a float4 register, flushed via ds_write_b128 on row change.
// NOTE launch_bounds min-waves MUST stay 4: at 6 the ~100-VGPR MFMA phase
// (Bh/Bl=64 regs) spills to scratch -> +300 MB HBM traffic (measured R7).
__global__ __launch_bounds__(256, 4) void gconv_mfma_kernel(
    const float* __restrict__ hin, const int* __restrict__ rowptr,
    const unsigned short* __restrict__ ebuf,
    const float* __restrict__ Wr, const float* __restrict__ Wt, const float* __restrict__ br,
    float* __restrict__ hout, float* __restrict__ stats)
{
    __shared__ float agg[64 * 68];                 // 17.4 KB
    __shared__ unsigned short erec[4 * RCAP];      // 4 KB

    int p = blockIdx.x;
    int xx = p & 7;
    int q = p >> 3;
    int sub = xx + 8 * (q >> 3);
    int tile = q & 7;
    int nb = (sub * 8 + tile) * 64;

    int tid = threadIdx.x;
    int w = tid >> 6;
    int l = tid & 63;

    for (int i = tid; i < 64 * 68 / 4; i += 256) ((float4*)agg)[i] = make_float4(0.f, 0.f, 0.f, 0.f);
    __syncthreads();

    // ---- gather ----
    int row0 = w * 16;                 // block-local first row of wave
    int qtr = l >> 4;                  // quarter 0..3
    int c4 = (l & 15) * 4;             // column base
    int r4 = row0 + qtr * 4;           // quarter's first block-local row
    int q0 = rowptr[nb + row0];        // wave range (uniform)
    int q1 = rowptr[nb + row0 + 16];
    int e0 = rowptr[nb + r4];          // quarter range
    int e1 = rowptr[nb + r4 + 4];

    const float* hsub = hin + (size_t)sub * 512 * 64;
    unsigned short* myrec = erec + w * RCAP;
    for (int i = l; i < q1 - q0; i += 64) myrec[i] = ebuf[q0 + i];
    __builtin_amdgcn_wave_barrier();

    int pos = e0 - q0;
    int pend = e1 - q0;
    float4 accv = make_float4(0.f, 0.f, 0.f, 0.f);
    int cur = r4;
    while (__ballot(pos < pend)) {
        bool active = pos < pend;
        int rp = active ? pos : 0;
        unsigned rec = myrec[rp];                       // ds_read_u16 (quarter-bcast)
        int d = rec >> 9;
        const float* srcp = hsub + (rec & 511) * 64 + c4;
        float4 v = *(const float4*)srcp;                // always in-bounds
        if (active) {
            if (d != cur) {
                *(float4*)(agg + cur * 68 + c4) = accv;
                accv = make_float4(0.f, 0.f, 0.f, 0.f);
                cur = d;
            }
            accv.x += v.x; accv.y += v.y; accv.z += v.z; accv.w += v.w;
            pos++;
        }
    }
    *(float4*)(agg + cur * 68 + c4) = accv;   // final flush (untouched rows stay 0)

    // ---- B fragments ----
    int nt = w >> 1;
    int ct = w & 1;
    int n_out = ct * 32 + (l & 31);
    int kh = l >> 5;

    bf16x8 Bh[8], Bl[8];
    #pragma unroll
    for (int kc = 0; kc < 8; kc++) {
        int kbase = kc * 16 + kh * 8;
        const float* wsrc = (kbase < 64) ? (Wr + n_out * 64 + kbase)
                                         : (Wt + n_out * 64 + (kbase - 64));
        float4 u0 = *(const float4*)(wsrc);
        float4 u1 = *(const float4*)(wsrc + 4);
        float vv[8] = {u0.x, u0.y, u0.z, u0.w, u1.x, u1.y, u1.z, u1.w};
        #pragma unroll
        for (int j = 0; j < 8; j++) {
            unsigned short hi = rne_bf16(vv[j]);
            float hif = __uint_as_float((unsigned int)hi << 16);
            Bh[kc][j] = (short)hi;
            Bl[kc][j] = (short)rne_bf16(vv[j] - hif);
        }
    }
    float bias = br[n_out];
    __syncthreads();

    // ---- MFMA: A = [agg | h], split-bf16 (hh, lh, hl) ----
    f32x16 acc;
    #pragma unroll
    for (int j = 0; j < 16; j++) acc[j] = bias;

    int row = nt * 32 + (l & 31);
    const float* hrow = hin + (size_t)(nb + row) * 64;
    #pragma unroll
    for (int kc = 0; kc < 8; kc++) {
        int k0 = kc * 16 + kh * 8;
        float vv[8];
        if (kc < 4) {
            float4 a0 = *(const float4*)(agg + row * 68 + k0);
            float4 a1 = *(const float4*)(agg + row * 68 + k0 + 4);
            vv[0]=a0.x; vv[1]=a0.y; vv[2]=a0.z; vv[3]=a0.w;
            vv[4]=a1.x; vv[5]=a1.y; vv[6]=a1.z; vv[7]=a1.w;
        } else {
            float4 a0 = *(const float4*)(hrow + k0 - 64);
            float4 a1 = *(const float4*)(hrow + k0 - 60);
            vv[0]=a0.x; vv[1]=a0.y; vv[2]=a0.z; vv[3]=a0.w;
            vv[4]=a1.x; vv[5]=a1.y; vv[6]=a1.z; vv[7]=a1.w;
        }
        bf16x8 ah, al;
        #pragma unroll
        for (int j = 0; j < 8; j++) {
            unsigned short hi = rne_bf16(vv[j]);
            float hif = __uint_as_float((unsigned int)hi << 16);
            ah[j] = (short)hi;
            al[j] = (short)rne_bf16(vv[j] - hif);
        }
        acc = __builtin_amdgcn_mfma_f32_32x32x16_bf16(ah, Bh[kc], acc, 0, 0, 0);
        acc = __builtin_amdgcn_mfma_f32_32x32x16_bf16(al, Bh[kc], acc, 0, 0, 0);
        acc = __builtin_amdgcn_mfma_f32_32x32x16_bf16(ah, Bl[kc], acc, 0, 0, 0);
    }

    // ---- epilogue: store h1 + BN stats ----
    float s = 0.f, qv = 0.f;
    #pragma unroll
    for (int j = 0; j < 16; j++) {
        int crow = (j & 3) + 8 * (j >> 2) + 4 * (l >> 5);
        int node = nb + nt * 32 + crow;
        float v = acc[j];
        hout[node * 64 + n_out] = v;
        s += v;
        qv += v * v;
    }
    s += __shfl_xor(s, 32, 64);
    qv += __shfl_xor(qv, 32, 64);
    int rep = p & 31;
    if ((l & 32) == 0) {
        atomicAdd(&stats[rep * 128 + n_out], s);
        atomicAdd(&stats[rep * 128 + 64 + n_out], qv);
    }
}

// ---------------- VALU gconv (512-node small graph) ----------
__global__ __launch_bounds__(512, 6) void gconv_kernel(
    const float* __restrict__ hin, const int* __restrict__ rowptr, const int* __restrict__ srcs,
    const float* __restrict__ Wr, const float* __restrict__ Wt, const float* __restrict__ br,
    float* __restrict__ hout, float* __restrict__ stats)
{
    __shared__ float wrt[4096];
    __shared__ float wtt[4096];
    __shared__ float4 aggT[8][64];
    __shared__ float4 hT[8][64];
    __shared__ float sbuf[8][64];
    __shared__ float qbuf[8][64];
    __shared__ float brs[64];

    int tid = threadIdx.x;
    for (int idx = tid; idx < 4096; idx += 512) {
        int cc = idx >> 6, kk = idx & 63;
        wrt[kk * 64 + ((kk + cc) & 63)] = Wr[idx];
        wtt[kk * 64 + ((kk + cc) & 63)] = Wt[idx];
    }
    if (tid < 64) brs[tid] = br[tid];
    __syncthreads();

    int w = tid >> 6;
    int c = tid & 63;
    int node0 = (blockIdx.x * 8 + w) * 4;

    float* aggp = (float*)&aggT[w][0];
    float* hp   = (float*)&hT[w][0];
    #pragma unroll
    for (int r = 0; r < 4; r++) {
        int node = node0 + r;
        hp[c * 4 + r] = hin[node * 64 + c];
        int e0 = rowptr[node], e1 = rowptr[node + 1];
        float a = 0.f;
        int e = e0;
        for (; e + 4 <= e1; e += 4) {
            int s0 = srcs[e], s1 = srcs[e + 1], s2 = srcs[e + 2], s3 = srcs[e + 3];
            float v0 = hin[s0 * 64 + c];
            float v1 = hin[s1 * 64 + c];
            float v2 = hin[s2 * 64 + c];
            float v3 = hin[s3 * 64 + c];
            a += (v0 + v1) + (v2 + v3);
        }
        for (; e < e1; e++) a += hin[srcs[e] * 64 + c];
        aggp[c * 4 + r] = a;
    }

    float o0 = brs[c], o1 = o0, o2 = o0, o3 = o0;
    #pragma unroll 8
    for (int k = 0; k < 64; k++) {
        float wr = wrt[k * 64 + ((k + c) & 63)];
        float wt = wtt[k * 64 + ((k + c) & 63)];
        float4 av = aggT[w][k];
        float4 hv = hT[w][k];
        o0 += wr * av.x + wt * hv.x;
        o1 += wr * av.y + wt * hv.y;
        o2 += wr * av.z + wt * hv.z;
        o3 += wr * av.w + wt * hv.w;
    }
    hout[(node0 + 0) * 64 + c] = o0;
    hout[(node0 + 1) * 64 + c] = o1;
    hout[(node0 + 2) * 64 + c] = o2;
    hout[(node0 + 3) * 64 + c] = o3;

    sbuf[w][c] = (o0 + o1) + (o2 + o3);
    qbuf[w][c] = (o0 * o0 + o1 * o1) + (o2 * o2 + o3 * o3);
    __syncthreads();
    int rep = blockIdx.x & 31;
    if (w == 0) {
        float s = 0.f;
        #pragma unroll
        for (int ww = 0; ww < 8; ww++) s += sbuf[ww][c];
        atomicAdd(&stats[rep * 128 + c], s);
    } else if (w == 1) {
        float q = 0.f;
        #pragma unroll
        for (int ww = 0; ww < 8; ww++) q += qbuf[ww][c];
        atomicAdd(&stats[rep * 128 + 64 + c], q);
    }
}

// ---------------- subgraph mean (only for the initial x) ----------------
__global__ void smean_kernel(const float* __restrict__ hin, float* __restrict__ xsum) {
    __shared__ float red[16][64];
    int t = threadIdx.x;
    int w = t >> 6, c = t & 63;
    int n = blockIdx.x;
    int base = n * 64 + c;
    float s = 0.f;
    #pragma unroll 8
    for (int j = 0; j < 32; j++) {
        int si = w * 32 + j;
        s += hin[si * 32768 + base];
    }
    red[w][c] = s;
    __syncthreads();
    if (w == 0) {
        float tot = 0.f;
        #pragma unroll
        for (int ww = 0; ww < 16; ww++) tot += red[ww][c];
        xsum[base] = tot * (1.f / 512.f);
    }
}

// ---- h = relu(bn(h1)+bn(h2)[n]) + next-layer smean, BN-finalize fused ----
__global__ __launch_bounds__(1024) void combine_smean_kernel(
    const float* __restrict__ h1, const float* __restrict__ h2,
    const float* __restrict__ stB, const float* __restrict__ stS,
    const float* __restrict__ gB, const float* __restrict__ bB,
    const float* __restrict__ gS, const float* __restrict__ bS,
    float* __restrict__ hout, float* __restrict__ xsum)
{
    __shared__ float bnp[256];
    __shared__ float red[16][64];
    int t = threadIdx.x;
    if (t < 64) {
        int c = t;
        float sb = 0.f, qb = 0.f, ss = 0.f, qs = 0.f;
        for (int r2 = 0; r2 < 32; r2++) {
            sb += stB[r2 * 128 + c];
            qb += stB[r2 * 128 + 64 + c];
            ss += stS[r2 * 128 + c];
            qs += stS[r2 * 128 + 64 + c];
        }
        float muB = sb * (1.f / 262144.f);
        float varB = qb * (1.f / 262144.f) - muB * muB;
        float scB = gB[c] * rsqrtf(varB + 1e-5f);
        bnp[c] = scB;
        bnp[64 + c] = bB[c] - muB * scB;
        float muS = ss * (1.f / 512.f);
        float varS = qs * (1.f / 512.f) - muS * muS;
        float scS = gS[c] * rsqrtf(varS + 1e-5f);
        bnp[128 + c] = scS;
        bnp[192 + c] = bS[c] - muS * scS;
    }
    __syncthreads();

    int w = t >> 6;
    int l = t & 63;
    int c4 = (l & 15) * 4;
    int r = l >> 4;
    int n = blockIdx.x;

    float4 sB = *(const float4*)(bnp + c4);
    float4 hB = *(const float4*)(bnp + 64 + c4);
    float4 sS = *(const float4*)(bnp + 128 + c4);
    float4 hS = *(const float4*)(bnp + 192 + c4);
    float4 b2 = *(const float4*)(h2 + n * 64 + c4);
    float bx = b2.x * sS.x + hS.x;
    float by = b2.y * sS.y + hS.y;
    float bz = b2.z * sS.z + hS.z;
    float bw = b2.w * sS.w + hS.w;

    float4 acc = make_float4(0.f, 0.f, 0.f, 0.f);
    #pragma unroll
    for (int j = 0; j < 8; j++) {
        int si = w * 32 + j * 4 + r;
        size_t base = (size_t)(si * 512 + n) * 64 + c4;
        float4 a = *(const float4*)(h1 + base);
        float4 v;
        v.x = fmaxf(a.x * sB.x + hB.x + bx, 0.f);
        v.y = fmaxf(a.y * sB.y + hB.y + by, 0.f);
        v.z = fmaxf(a.z * sB.z + hB.z + bz, 0.f);
        v.w = fmaxf(a.w * sB.w + hB.w + bw, 0.f);
        *(float4*)(hout + base) = v;
        acc.x += v.x; acc.y += v.y; acc.z += v.z; acc.w += v.w;
    }
    acc.x += __shfl_xor(acc.x, 16, 64); acc.y += __shfl_xor(acc.y, 16, 64);
    acc.z += __shfl_xor(acc.z, 16, 64); acc.w += __shfl_xor(acc.w, 16, 64);
    acc.x += __shfl_xor(acc.x, 32, 64); acc.y += __shfl_xor(acc.y, 32, 64);
    acc.z += __shfl_xor(acc.z, 32, 64); acc.w += __shfl_xor(acc.w, 32, 64);
    if (l < 16) {
        red[w][c4 + 0] = acc.x;
        red[w][c4 + 1] = acc.y;
        red[w][c4 + 2] = acc.z;
        red[w][c4 + 3] = acc.w;
    }
    __syncthreads();
    if (t < 64) {
        float tot = 0.f;
        #pragma unroll
        for (int ww = 0; ww < 16; ww++) tot += red[ww][t];
        xsum[n * 64 + t] = tot * (1.f / 512.f);
    }
}

// ---------------- head ----------------
__global__ void head_kernel(const float* __restrict__ xs, const float* __restrict__ W1,
                            const float* __restrict__ b1, const float* __restrict__ W2,
                            const float* __restrict__ b2, float* __restrict__ out) {
    __shared__ float z[64];
    __shared__ float hid[128];
    int t = threadIdx.x;
    int n = blockIdx.x;
    if (t < 64) {
        float v = xs[n * 64 + t];
        float m = v;
        for (int off = 32; off >= 1; off >>= 1) m = fmaxf(m, __shfl_xor(m, off, 64));
        float e = expf(v - m);
        float s = e;
        for (int off = 32; off >= 1; off >>= 1) s += __shfl_xor(s, off, 64);
        z[t] = v - m - logf(s);
    }
    __syncthreads();
    {
        float acc = b1[t];
        const float* wrow = W1 + t * 64;
        #pragma unroll 8
        for (int k = 0; k < 64; k++) acc += z[k] * wrow[k];
        hid[t] = fmaxf(acc, 0.f);
    }
    __syncthreads();
    if (t < 10) {
        float o = b2[t];
        const float* wrow = W2 + t * 128;
        #pragma unroll 8
        for (int j = 0; j < 128; j++) o += hid[j] * wrow[j];
        out[n * 10 + t] = o;
    }
}

extern "C" void kernel_launch(void* const* d_in, const int* in_sizes, int n_in,
                              void* d_out, int out_size, void* d_ws, size_t ws_size,
                              hipStream_t stream) {
    const float* x       = (const float*)d_in[0];
    const float* Wrel    = (const float*)d_in[1];
    const float* brel    = (const float*)d_in[2];
    const float* Wroot   = (const float*)d_in[3];
    const float* bn_g    = (const float*)d_in[4];
    const float* bn_b    = (const float*)d_in[5];
    const float* Wrel_s  = (const float*)d_in[6];
    const float* brel_s  = (const float*)d_in[7];
    const float* Wroot_s = (const float*)d_in[8];
    const float* bns_g   = (const float*)d_in[9];
    const float* bns_b   = (const float*)d_in[10];
    const float* W1      = (const float*)d_in[11];
    const float* b1      = (const float*)d_in[12];
    const float* W2      = (const float*)d_in[13];
    const float* b2      = (const float*)d_in[14];
    const int* ei        = (const int*)d_in[15];
    const int* oei       = (const int*)d_in[16];
    float* out = (float*)d_out;

    char* ws = (char*)d_ws;
    size_t off = 0;
    auto alloc = [&](size_t bytes) -> void* {
        void* p = ws + off;
        off = (off + bytes + 255) & ~(size_t)255;
        return p;
    };
    float* h     = (float*)alloc((size_t)NT * 64 * 4);
    float* h1    = (float*)alloc((size_t)NT * 64 * 4);
    float* xsum  = (float*)alloc(NS * 64 * 4);
    float* h2    = (float*)alloc(NS * 64 * 4);
    float* stats = (float*)alloc(NLAYER * 2 * 4096 * 4);
    int* deg     = (int*)alloc((size_t)NT * 4);
    int* rowptr  = (int*)alloc((size_t)(NT + 1) * 4);
    int* cursor  = (int*)alloc((size_t)NT * 4);
    int* bsum    = (int*)alloc(256 * 4);
    unsigned short* ebuf = (unsigned short*)alloc((size_t)ES * 2);
    int* rowptrS = (int*)alloc(513 * 4);
    int* srcsS   = (int*)alloc(EO * 4);
    (void)ws_size; (void)in_sizes; (void)n_in; (void)out_size;

    hipMemsetAsync(deg, 0, (size_t)NT * 4, stream);
    hipMemsetAsync(stats, 0, (size_t)NLAYER * 2 * 4096 * 4, stream);

    hist_xcd_kernel<<<ES / EPB * 8, 256, 0, stream>>>(ei + ES, deg);
    scan1_kernel<<<NT / 1024, 1024, 0, stream>>>(deg, rowptr, bsum);
    scan2_kernel<<<1, 256, 0, stream>>>(bsum);
    scan3_kernel<<<NT / 1024, 1024, 0, stream>>>(rowptr, bsum, cursor);
    scatter_xcd_kernel<<<ES / EPB * 8, 256, 0, stream>>>(ei, cursor, ebuf);
    small_csr_kernel<<<1, 1024, 0, stream>>>(oei, rowptrS, srcsS);

    smean_kernel<<<NS, 1024, 0, stream>>>(x, xsum);   // xsum of layer-0 input

    for (int i = 0; i < NLAYER; i++) {
        const float* hin = (i == 0) ? x : h;
        float* stB = stats + i * 8192;
        float* stS = stB + 4096;
        gconv_mfma_kernel<<<NT / 64, 256, 0, stream>>>(hin, rowptr, ebuf,
            Wrel + i * 4096, Wroot + i * 4096, brel + i * 64, h1, stB);
        gconv_kernel<<<NS / 32, 512, 0, stream>>>(xsum, rowptrS, srcsS,
            Wrel_s + i * 4096, Wroot_s + i * 4096, brel_s + i * 64, h2, stS);
        combine_smean_kernel<<<NS, 1024, 0, stream>>>(h1, h2, stB, stS,
            bn_g + i * 64, bn_b + i * 64, bns_g + i * 64, bns_b + i * 64, h, xsum);
    }
    head_kernel<<<NS, 128, 0, stream>>>(xsum, W1, b1, W2, b2, out);
}

// Round 9
// 859.144 us; speedup vs baseline: 1.1757x; 1.0894x over previous
//
#include <hip/hip_runtime.h>
#include <math.h>

#define NT 262144
#define NS 512
#define ES 2097152
#define EP 3145728      // padded edge capacity (<= 2M + 3*256K = 2.75M)
#define EO 8192
#define NLAYER 4
#define RCAP 512        // per-wave record stage (padded mean ~152, huge margin)
#define EPB 4096        // edges per scatter/hist block-chunk

typedef short bf16x8 __attribute__((ext_vector_type(8)));
typedef float f32x16 __attribute__((ext_vector_type(16)));

__device__ inline unsigned short rne_bf16(float f) {
    unsigned int u = __float_as_uint(f);
    u += 0x7FFF + ((u >> 16) & 1);
    return (unsigned short)(u >> 16);
}

// ---------------- per-node CSR build, XCD-partitioned, ROW-PADDED to x4 ----
__global__ void hist_xcd_kernel(const int* __restrict__ dst, int* __restrict__ deg) {
    int p = blockIdx.x;
    int g = p & 7;
    int base = (p >> 3) * EPB;
    for (int i = threadIdx.x; i < EPB; i += 256) {
        int d = dst[base + i];
        if (((d >> 9) & 7) == g) atomicAdd(&deg[d], 1);
    }
}

// scan over PADDED degrees: rowptr boundaries all 4-aligned
__global__ void scan1_kernel(const int* __restrict__ deg, int* __restrict__ rowptr,
                             int* __restrict__ bsum) {
    __shared__ int lds[1024];
    int t = threadIdx.x;
    int g = blockIdx.x * 1024 + t;
    int v = (deg[g] + 3) & ~3;
    lds[t] = v;
    __syncthreads();
    for (int off = 1; off < 1024; off <<= 1) {
        int x = (t >= off) ? lds[t - off] : 0;
        __syncthreads();
        lds[t] += x;
        __syncthreads();
    }
    rowptr[g] = lds[t] - v;
    if (t == 1023) bsum[blockIdx.x] = lds[t];
}

__global__ void scan2_kernel(int* bsum) {
    __shared__ int lds[256];
    int t = threadIdx.x;
    int v = bsum[t];
    lds[t] = v;
    __syncthreads();
    for (int off = 1; off < 256; off <<= 1) {
        int x = (t >= off) ? lds[t - off] : 0;
        __syncthreads();
        lds[t] += x;
        __syncthreads();
    }
    bsum[t] = lds[t] - v;
}

__global__ void scan3_kernel(int* __restrict__ rowptr, const int* __restrict__ bsum,
                             int* __restrict__ cursor, const int* __restrict__ deg) {
    int t = threadIdx.x;
    int g = blockIdx.x * 1024 + t;
    int v = rowptr[g] + bsum[blockIdx.x];
    rowptr[g] = v;
    cursor[g] = v;
    if (g == NT - 1) rowptr[NT] = v + ((deg[g] + 3) & ~3);
}

// ebuf pre-memset to 0xFF: pad slots keep sentinel 0xFFFF
__global__ void scatter_xcd_kernel(const int* __restrict__ ei, int* __restrict__ cur,
                                   unsigned short* __restrict__ ebuf) {
    int p = blockIdx.x;
    int g = p & 7;
    int base = (p >> 3) * EPB;
    for (int i = threadIdx.x; i < EPB; i += 256) {
        int d = ei[ES + base + i];
        if (((d >> 9) & 7) == g) {
            int s = ei[base + i];
            int pos = atomicAdd(&cur[d], 1);
            ebuf[pos] = (unsigned short)((s & 511) | ((d & 63) << 9));
        }
    }
}

// ---------------- CSR build (small graph, single block) ----------------
__global__ void small_csr_kernel(const int* __restrict__ oei, int* __restrict__ rowptrS,
                                 int* __restrict__ srcsS) {
    __shared__ int sdeg[NS];
    __shared__ int scur[NS];
    int t = threadIdx.x;
    if (t < NS) sdeg[t] = 0;
    __syncthreads();
    for (int e = t; e < EO; e += 1024) atomicAdd(&sdeg[oei[EO + e]], 1);
    __syncthreads();
    int myv = (t < NS) ? sdeg[t] : 0;
    __syncthreads();
    for (int off = 1; off < NS; off <<= 1) {
        int x = (t >= off && t < NS) ? sdeg[t - off] : 0;
        __syncthreads();
        if (t < NS) sdeg[t] += x;
        __syncthreads();
    }
    if (t < NS) {
        int excl = sdeg[t] - myv;
        rowptrS[t] = excl;
        scur[t] = excl;
        if (t == 0) rowptrS[NS] = EO;
    }
    __syncthreads();
    for (int e = t; e < EO; e += 1024) {
        int d = oei[EO + e];
        int pos = atomicAdd(&scur[d], 1);
        srcsS[pos] = oei[e];
    }
}

// ---------------- MFMA gconv: row-bounded pad-aligned pipelined gather ------
// Block = one 64-node tile (XCD swizzle: subgraph's 8 tiles on one XCD; gather
// L2-resident — verified R3). Wave w owns rows [w*16,w*16+16); each 16-lane
// quarter owns 4 rows. Row edge-lists are padded to x4 with 0xFFFF sentinels,
// so the inner loop is exact batches of 4: 1 aligned ds_read_b64 (4 recs) +
// 4 independent global_load_dwordx4 (4-deep in flight) + 16 mask-FMAs.
// No run detection, no ballot, no remainder.
// NOTE launch_bounds min-waves MUST stay 4: at 6 the ~100-VGPR MFMA phase
// spills to scratch -> +300 MB HBM traffic (measured R7).
__global__ __launch_bounds__(256, 4) void gconv_mfma_kernel(
    const float* __restrict__ hin, const int* __restrict__ rowptr,
    const unsigned short* __restrict__ ebuf,
    const float* __restrict__ Wr, const float* __restrict__ Wt, const float* __restrict__ br,
    float* __restrict__ hout, float* __restrict__ stats)
{
    __shared__ float agg[64 * 68];                 // 17.4 KB
    __shared__ unsigned short erec[4 * RCAP];      // 4 KB

    int p = blockIdx.x;
    int xx = p & 7;
    int q = p >> 3;
    int sub = xx + 8 * (q >> 3);
    int tile = q & 7;
    int nb = (sub * 8 + tile) * 64;

    int tid = threadIdx.x;
    int w = tid >> 6;
    int l = tid & 63;

    // ---- gather ----
    int row0 = w * 16;
    int qtr = l >> 4;
    int c4 = (l & 15) * 4;
    int r4 = row0 + qtr * 4;
    int q0 = rowptr[nb + row0];            // wave range start (4-aligned)
    int q1 = rowptr[nb + row0 + 16];

    const float* hsub = hin + (size_t)sub * 512 * 64;
    unsigned short* myrec = erec + w * RCAP;
    for (int i = l; i < q1 - q0; i += 64) myrec[i] = ebuf[q0 + i];
    __builtin_amdgcn_wave_barrier();

    #pragma unroll
    for (int j = 0; j < 4; j++) {
        int row = r4 + j;
        int e0 = rowptr[nb + row] - q0;     // 4-aligned within stage
        int e1 = rowptr[nb + row + 1] - q0;
        float4 accv = make_float4(0.f, 0.f, 0.f, 0.f);
        for (int pos = e0; pos < e1; pos += 4) {
            uint2 rr = *(const uint2*)(myrec + pos);   // ds_read_b64, aligned
            unsigned r0 = rr.x & 0xffffu, r1 = rr.x >> 16;
            unsigned r2 = rr.y & 0xffffu, r3 = rr.y >> 16;
            float m0 = (r0 != 0xffffu) ? 1.f : 0.f;
            float m1 = (r1 != 0xffffu) ? 1.f : 0.f;
            float m2 = (r2 != 0xffffu) ? 1.f : 0.f;
            float m3 = (r3 != 0xffffu) ? 1.f : 0.f;
            float4 v0 = *(const float4*)(hsub + (r0 & 511) * 64 + c4);
            float4 v1 = *(const float4*)(hsub + (r1 & 511) * 64 + c4);
            float4 v2 = *(const float4*)(hsub + (r2 & 511) * 64 + c4);
            float4 v3 = *(const float4*)(hsub + (r3 & 511) * 64 + c4);
            accv.x += v0.x * m0 + v1.x * m1 + v2.x * m2 + v3.x * m3;
            accv.y += v0.y * m0 + v1.y * m1 + v2.y * m2 + v3.y * m3;
            accv.z += v0.z * m0 + v1.z * m1 + v2.z * m2 + v3.z * m3;
            accv.w += v0.w * m0 + v1.w * m1 + v2.w * m2 + v3.w * m3;
        }
        *(float4*)(agg + row * 68 + c4) = accv;   // one flush per row (0 if no edges)
    }

    // ---- B fragments ----
    int nt = w >> 1;
    int ct = w & 1;
    int n_out = ct * 32 + (l & 31);
    int kh = l >> 5;

    bf16x8 Bh[8], Bl[8];
    #pragma unroll
    for (int kc = 0; kc < 8; kc++) {
        int kbase = kc * 16 + kh * 8;
        const float* wsrc = (kbase < 64) ? (Wr + n_out * 64 + kbase)
                                         : (Wt + n_out * 64 + (kbase - 64));
        float4 u0 = *(const float4*)(wsrc);
        float4 u1 = *(const float4*)(wsrc + 4);
        float vv[8] = {u0.x, u0.y, u0.z, u0.w, u1.x, u1.y, u1.z, u1.w};
        #pragma unroll
        for (int j = 0; j < 8; j++) {
            unsigned short hi = rne_bf16(vv[j]);
            float hif = __uint_as_float((unsigned int)hi << 16);
            Bh[kc][j] = (short)hi;
            Bl[kc][j] = (short)rne_bf16(vv[j] - hif);
        }
    }
    float bias = br[n_out];
    __syncthreads();

    // ---- MFMA: A = [agg | h], split-bf16 (hh, lh, hl) ----
    f32x16 acc;
    #pragma unroll
    for (int j = 0; j < 16; j++) acc[j] = bias;

    int row = nt * 32 + (l & 31);
    const float* hrow = hin + (size_t)(nb + row) * 64;
    #pragma unroll
    for (int kc = 0; kc < 8; kc++) {
        int k0 = kc * 16 + kh * 8;
        float vv[8];
        if (kc < 4) {
            float4 a0 = *(const float4*)(agg + row * 68 + k0);
            float4 a1 = *(const float4*)(agg + row * 68 + k0 + 4);
            vv[0]=a0.x; vv[1]=a0.y; vv[2]=a0.z; vv[3]=a0.w;
            vv[4]=a1.x; vv[5]=a1.y; vv[6]=a1.z; vv[7]=a1.w;
        } else {
            float4 a0 = *(const float4*)(hrow + k0 - 64);
            float4 a1 = *(const float4*)(hrow + k0 - 60);
            vv[0]=a0.x; vv[1]=a0.y; vv[2]=a0.z; vv[3]=a0.w;
            vv[4]=a1.x; vv[5]=a1.y; vv[6]=a1.z; vv[7]=a1.w;
        }
        bf16x8 ah, al;
        #pragma unroll
        for (int j = 0; j < 8; j++) {
            unsigned short hi = rne_bf16(vv[j]);
            float hif = __uint_as_float((unsigned int)hi << 16);
            ah[j] = (short)hi;
            al[j] = (short)rne_bf16(vv[j] - hif);
        }
        acc = __builtin_amdgcn_mfma_f32_32x32x16_bf16(ah, Bh[kc], acc, 0, 0, 0);
        acc = __builtin_amdgcn_mfma_f32_32x32x16_bf16(al, Bh[kc], acc, 0, 0, 0);
        acc = __builtin_amdgcn_mfma_f32_32x32x16_bf16(ah, Bl[kc], acc, 0, 0, 0);
    }

    // ---- epilogue: store h1 + BN stats ----
    float s = 0.f, qv = 0.f;
    #pragma unroll
    for (int j = 0; j < 16; j++) {
        int crow = (j & 3) + 8 * (j >> 2) + 4 * (l >> 5);
        int node = nb + nt * 32 + crow;
        float v = acc[j];
        hout[node * 64 + n_out] = v;
        s += v;
        qv += v * v;
    }
    s += __shfl_xor(s, 32, 64);
    qv += __shfl_xor(qv, 32, 64);
    int rep = p & 31;
    if ((l & 32) == 0) {
        atomicAdd(&stats[rep * 128 + n_out], s);
        atomicAdd(&stats[rep * 128 + 64 + n_out], qv);
    }
}

// ---------------- VALU gconv (512-node small graph) ----------
__global__ __launch_bounds__(512, 6) void gconv_kernel(
    const float* __restrict__ hin, const int* __restrict__ rowptr, const int* __restrict__ srcs,
    const float* __restrict__ Wr, const float* __restrict__ Wt, const float* __restrict__ br,
    float* __restrict__ hout, float* __restrict__ stats)
{
    __shared__ float wrt[4096];
    __shared__ float wtt[4096];
    __shared__ float4 aggT[8][64];
    __shared__ float4 hT[8][64];
    __shared__ float sbuf[8][64];
    __shared__ float qbuf[8][64];
    __shared__ float brs[64];

    int tid = threadIdx.x;
    for (int idx = tid; idx < 4096; idx += 512) {
        int cc = idx >> 6, kk = idx & 63;
        wrt[kk * 64 + ((kk + cc) & 63)] = Wr[idx];
        wtt[kk * 64 + ((kk + cc) & 63)] = Wt[idx];
    }
    if (tid < 64) brs[tid] = br[tid];
    __syncthreads();

    int w = tid >> 6;
    int c = tid & 63;
    int node0 = (blockIdx.x * 8 + w) * 4;

    float* aggp = (float*)&aggT[w][0];
    float* hp   = (float*)&hT[w][0];
    #pragma unroll
    for (int r = 0; r < 4; r++) {
        int node = node0 + r;
        hp[c * 4 + r] = hin[node * 64 + c];
        int e0 = rowptr[node], e1 = rowptr[node + 1];
        float a = 0.f;
        int e = e0;
        for (; e + 4 <= e1; e += 4) {
            int s0 = srcs[e], s1 = srcs[e + 1], s2 = srcs[e + 2], s3 = srcs[e + 3];
            float v0 = hin[s0 * 64 + c];
            float v1 = hin[s1 * 64 + c];
            float v2 = hin[s2 * 64 + c];
            float v3 = hin[s3 * 64 + c];
            a += (v0 + v1) + (v2 + v3);
        }
        for (; e < e1; e++) a += hin[srcs[e] * 64 + c];
        aggp[c * 4 + r] = a;
    }

    float o0 = brs[c], o1 = o0, o2 = o0, o3 = o0;
    #pragma unroll 8
    for (int k = 0; k < 64; k++) {
        float wr = wrt[k * 64 + ((k + c) & 63)];
        float wt = wtt[k * 64 + ((k + c) & 63)];
        float4 av = aggT[w][k];
        float4 hv = hT[w][k];
        o0 += wr * av.x + wt * hv.x;
        o1 += wr * av.y + wt * hv.y;
        o2 += wr * av.z + wt * hv.z;
        o3 += wr * av.w + wt * hv.w;
    }
    hout[(node0 + 0) * 64 + c] = o0;
    hout[(node0 + 1) * 64 + c] = o1;
    hout[(node0 + 2) * 64 + c] = o2;
    hout[(node0 + 3) * 64 + c] = o3;

    sbuf[w][c] = (o0 + o1) + (o2 + o3);
    qbuf[w][c] = (o0 * o0 + o1 * o1) + (o2 * o2 + o3 * o3);
    __syncthreads();
    int rep = blockIdx.x & 31;
    if (w == 0) {
        float s = 0.f;
        #pragma unroll
        for (int ww = 0; ww < 8; ww++) s += sbuf[ww][c];
        atomicAdd(&stats[rep * 128 + c], s);
    } else if (w == 1) {
        float q = 0.f;
        #pragma unroll
        for (int ww = 0; ww < 8; ww++) q += qbuf[ww][c];
        atomicAdd(&stats[rep * 128 + 64 + c], q);
    }
}

// ---------------- subgraph mean (only for the initial x) ----------------
__global__ void smean_kernel(const float* __restrict__ hin, float* __restrict__ xsum) {
    __shared__ float red[16][64];
    int t = threadIdx.x;
    int w = t >> 6, c = t & 63;
    int n = blockIdx.x;
    int base = n * 64 + c;
    float s = 0.f;
    #pragma unroll 8
    for (int j = 0; j < 32; j++) {
        int si = w * 32 + j;
        s += hin[si * 32768 + base];
    }
    red[w][c] = s;
    __syncthreads();
    if (w == 0) {
        float tot = 0.f;
        #pragma unroll
        for (int ww = 0; ww < 16; ww++) tot += red[ww][c];
        xsum[base] = tot * (1.f / 512.f);
    }
}

// ---- h = relu(bn(h1)+bn(h2)[n]) + next-layer smean, BN-finalize fused ----
__global__ __launch_bounds__(1024) void combine_smean_kernel(
    const float* __restrict__ h1, const float* __restrict__ h2,
    const float* __restrict__ stB, const float* __restrict__ stS,
    const float* __restrict__ gB, const float* __restrict__ bB,
    const float* __restrict__ gS, const float* __restrict__ bS,
    float* __restrict__ hout, float* __restrict__ xsum)
{
    __shared__ float bnp[256];
    __shared__ float red[16][64];
    int t = threadIdx.x;
    if (t < 64) {
        int c = t;
        float sb = 0.f, qb = 0.f, ss = 0.f, qs = 0.f;
        for (int r2 = 0; r2 < 32; r2++) {
            sb += stB[r2 * 128 + c];
            qb += stB[r2 * 128 + 64 + c];
            ss += stS[r2 * 128 + c];
            qs += stS[r2 * 128 + 64 + c];
        }
        float muB = sb * (1.f / 262144.f);
        float varB = qb * (1.f / 262144.f) - muB * muB;
        float scB = gB[c] * rsqrtf(varB + 1e-5f);
        bnp[c] = scB;
        bnp[64 + c] = bB[c] - muB * scB;
        float muS = ss * (1.f / 512.f);
        float varS = qs * (1.f / 512.f) - muS * muS;
        float scS = gS[c] * rsqrtf(varS + 1e-5f);
        bnp[128 + c] = scS;
        bnp[192 + c] = bS[c] - muS * scS;
    }
    __syncthreads();

    int w = t >> 6;
    int l = t & 63;
    int c4 = (l & 15) * 4;
    int r = l >> 4;
    int n = blockIdx.x;

    float4 sB = *(const float4*)(bnp + c4);
    float4 hB = *(const float4*)(bnp + 64 + c4);
    float4 sS = *(const float4*)(bnp + 128 + c4);
    float4 hS = *(const float4*)(bnp + 192 + c4);
    float4 b2 = *(const float4*)(h2 + n * 64 + c4);
    float bx = b2.x * sS.x + hS.x;
    float by = b2.y * sS.y + hS.y;
    float bz = b2.z * sS.z + hS.z;
    float bw = b2.w * sS.w + hS.w;

    float4 acc = make_float4(0.f, 0.f, 0.f, 0.f);
    #pragma unroll
    for (int j = 0; j < 8; j++) {
        int si = w * 32 + j * 4 + r;
        size_t base = (size_t)(si * 512 + n) * 64 + c4;
        float4 a = *(const float4*)(h1 + base);
        float4 v;
        v.x = fmaxf(a.x * sB.x + hB.x + bx, 0.f);
        v.y = fmaxf(a.y * sB.y + hB.y + by, 0.f);
        v.z = fmaxf(a.z * sB.z + hB.z + bz, 0.f);
        v.w = fmaxf(a.w * sB.w + hB.w + bw, 0.f);
        *(float4*)(hout + base) = v;
        acc.x += v.x; acc.y += v.y; acc.z += v.z; acc.w += v.w;
    }
    acc.x += __shfl_xor(acc.x, 16, 64); acc.y += __shfl_xor(acc.y, 16, 64);
    acc.z += __shfl_xor(acc.z, 16, 64); acc.w += __shfl_xor(acc.w, 16, 64);
    acc.x += __shfl_xor(acc.x, 32, 64); acc.y += __shfl_xor(acc.y, 32, 64);
    acc.z += __shfl_xor(acc.z, 32, 64); acc.w += __shfl_xor(acc.w, 32, 64);
    if (l < 16) {
        red[w][c4 + 0] = acc.x;
        red[w][c4 + 1] = acc.y;
        red[w][c4 + 2] = acc.z;
        red[w][c4 + 3] = acc.w;
    }
    __syncthreads();
    if (t < 64) {
        float tot = 0.f;
        #pragma unroll
        for (int ww = 0; ww < 16; ww++) tot += red[ww][t];
        xsum[n * 64 + t] = tot * (1.f / 512.f);
    }
}

// ---------------- head ----------------
__global__ void head_kernel(const float* __restrict__ xs, const float* __restrict__ W1,
                            const float* __restrict__ b1, const float* __restrict__ W2,
                            const float* __restrict__ b2, float* __restrict__ out) {
    __shared__ float z[64];
    __shared__ float hid[128];
    int t = threadIdx.x;
    int n = blockIdx.x;
    if (t < 64) {
        float v = xs[n * 64 + t];
        float m = v;
        for (int off = 32; off >= 1; off >>= 1) m = fmaxf(m, __shfl_xor(m, off, 64));
        float e = expf(v - m);
        float s = e;
        for (int off = 32; off >= 1; off >>= 1) s += __shfl_xor(s, off, 64);
        z[t] = v - m - logf(s);
    }
    __syncthreads();
    {
        float acc = b1[t];
        const float* wrow = W1 + t * 64;
        #pragma unroll 8
        for (int k = 0; k < 64; k++) acc += z[k] * wrow[k];
        hid[t] = fmaxf(acc, 0.f);
    }
    __syncthreads();
    if (t < 10) {
        float o = b2[t];
        const float* wrow = W2 + t * 128;
        #pragma unroll 8
        for (int j = 0; j < 128; j++) o += hid[j] * wrow[j];
        out[n * 10 + t] = o;
    }
}

extern "C" void kernel_launch(void* const* d_in, const int* in_sizes, int n_in,
                              void* d_out, int out_size, void* d_ws, size_t ws_size,
                              hipStream_t stream) {
    const float* x       = (const float*)d_in[0];
    const float* Wrel    = (const float*)d_in[1];
    const float* brel    = (const float*)d_in[2];
    const float* Wroot   = (const float*)d_in[3];
    const float* bn_g    = (const float*)d_in[4];
    const float* bn_b    = (const float*)d_in[5];
    const float* Wrel_s  = (const float*)d_in[6];
    const float* brel_s  = (const float*)d_in[7];
    const float* Wroot_s = (const float*)d_in[8];
    const float* bns_g   = (const float*)d_in[9];
    const float* bns_b   = (const float*)d_in[10];
    const float* W1      = (const float*)d_in[11];
    const float* b1      = (const float*)d_in[12];
    const float* W2      = (const float*)d_in[13];
    const float* b2      = (const float*)d_in[14];
    const int* ei        = (const int*)d_in[15];
    const int* oei       = (const int*)d_in[16];
    float* out = (float*)d_out;

    char* ws = (char*)d_ws;
    size_t off = 0;
    auto alloc = [&](size_t bytes) -> void* {
        void* p = ws + off;
        off = (off + bytes + 255) & ~(size_t)255;
        return p;
    };
    float* h     = (float*)alloc((size_t)NT * 64 * 4);
    float* h1    = (float*)alloc((size_t)NT * 64 * 4);
    float* xsum  = (float*)alloc(NS * 64 * 4);
    float* h2    = (float*)alloc(NS * 64 * 4);
    float* stats = (float*)alloc(NLAYER * 2 * 4096 * 4);
    int* deg     = (int*)alloc((size_t)NT * 4);
    int* rowptr  = (int*)alloc((size_t)(NT + 1) * 4);
    int* cursor  = (int*)alloc((size_t)NT * 4);
    int* bsum    = (int*)alloc(256 * 4);
    unsigned short* ebuf = (unsigned short*)alloc((size_t)EP * 2);
    int* rowptrS = (int*)alloc(513 * 4);
    int* srcsS   = (int*)alloc(EO * 4);
    (void)ws_size; (void)in_sizes; (void)n_in; (void)out_size;

    hipMemsetAsync(deg, 0, (size_t)NT * 4, stream);
    hipMemsetAsync(stats, 0, (size_t)NLAYER * 2 * 4096 * 4, stream);
    hipMemsetAsync(ebuf, 0xFF, (size_t)EP * 2, stream);   // pad slots = 0xFFFF sentinel

    hist_xcd_kernel<<<ES / EPB * 8, 256, 0, stream>>>(ei + ES, deg);
    scan1_kernel<<<NT / 1024, 1024, 0, stream>>>(deg, rowptr, bsum);
    scan2_kernel<<<1, 256, 0, stream>>>(bsum);
    scan3_kernel<<<NT / 1024, 1024, 0, stream>>>(rowptr, bsum, cursor, deg);
    scatter_xcd_kernel<<<ES / EPB * 8, 256, 0, stream>>>(ei, cursor, ebuf);
    small_csr_kernel<<<1, 1024, 0, stream>>>(oei, rowptrS, srcsS);

    smean_kernel<<<NS, 1024, 0, stream>>>(x, xsum);   // xsum of layer-0 input

    for (int i = 0; i < NLAYER; i++) {
        const float* hin = (i == 0) ? x : h;
        float* stB = stats + i * 8192;
        float* stS = stB + 4096;
        gconv_mfma_kernel<<<NT / 64, 256, 0, stream>>>(hin, rowptr, ebuf,
            Wrel + i * 4096, Wroot + i * 4096, brel + i * 64, h1, stB);
        gconv_kernel<<<NS / 32, 512, 0, stream>>>(xsum, rowptrS, srcsS,
            Wrel_s + i * 4096, Wroot_s + i * 4096, brel_s + i * 64, h2, stS);
        combine_smean_kernel<<<NS, 1024, 0, stream>>>(h1, h2, stB, stS,
            bn_g + i * 64, bn_b + i * 64, bns_g + i * 64, bns_b + i * 64, h, xsum);
    }
    head_kernel<<<NS, 128, 0, stream>>>(xsum, W1, b1, W2, b2, out);
}

// Round 10
// 855.985 us; speedup vs baseline: 1.1801x; 1.0037x over previous
//
#include <hip/hip_runtime.h>
#include <math.h>

#define NT 262144
#define NS 512
#define ES 2097152
#define EP 3145728      // padded edge capacity
#define EO 8192
#define NLAYER 4
#define RCAP 1536       // per-tile record stage (padded mean ~640, +40 sigma)
#define EPB 4096        // edges per scatter/hist block-chunk

typedef short bf16x8 __attribute__((ext_vector_type(8)));
typedef float f32x16 __attribute__((ext_vector_type(16)));

__device__ inline unsigned short rne_bf16(float f) {
    unsigned int u = __float_as_uint(f);
    u += 0x7FFF + ((u >> 16) & 1);
    return (unsigned short)(u >> 16);
}

// ---------------- per-node CSR build, XCD-partitioned, ROW-PADDED to x4 ----
__global__ void hist_xcd_kernel(const int* __restrict__ dst, int* __restrict__ deg) {
    int p = blockIdx.x;
    int g = p & 7;
    int base = (p >> 3) * EPB;
    for (int i = threadIdx.x; i < EPB; i += 256) {
        int d = dst[base + i];
        if (((d >> 9) & 7) == g) atomicAdd(&deg[d], 1);
    }
}

__global__ void scan1_kernel(const int* __restrict__ deg, int* __restrict__ rowptr,
                             int* __restrict__ bsum) {
    __shared__ int lds[1024];
    int t = threadIdx.x;
    int g = blockIdx.x * 1024 + t;
    int v = (deg[g] + 3) & ~3;
    lds[t] = v;
    __syncthreads();
    for (int off = 1; off < 1024; off <<= 1) {
        int x = (t >= off) ? lds[t - off] : 0;
        __syncthreads();
        lds[t] += x;
        __syncthreads();
    }
    rowptr[g] = lds[t] - v;
    if (t == 1023) bsum[blockIdx.x] = lds[t];
}

__global__ void scan2_kernel(int* bsum) {
    __shared__ int lds[256];
    int t = threadIdx.x;
    int v = bsum[t];
    lds[t] = v;
    __syncthreads();
    for (int off = 1; off < 256; off <<= 1) {
        int x = (t >= off) ? lds[t - off] : 0;
        __syncthreads();
        lds[t] += x;
        __syncthreads();
    }
    bsum[t] = lds[t] - v;
}

__global__ void scan3_kernel(int* __restrict__ rowptr, const int* __restrict__ bsum,
                             int* __restrict__ cursor, const int* __restrict__ deg) {
    int t = threadIdx.x;
    int g = blockIdx.x * 1024 + t;
    int v = rowptr[g] + bsum[blockIdx.x];
    rowptr[g] = v;
    cursor[g] = v;
    if (g == NT - 1) rowptr[NT] = v + ((deg[g] + 3) & ~3);
}

__global__ void scatter_xcd_kernel(const int* __restrict__ ei, int* __restrict__ cur,
                                   unsigned short* __restrict__ ebuf) {
    int p = blockIdx.x;
    int g = p & 7;
    int base = (p >> 3) * EPB;
    for (int i = threadIdx.x; i < EPB; i += 256) {
        int d = ei[ES + base + i];
        if (((d >> 9) & 7) == g) {
            int s = ei[base + i];
            int pos = atomicAdd(&cur[d], 1);
            ebuf[pos] = (unsigned short)((s & 511) | ((d & 63) << 9));
        }
    }
}

// ---------------- CSR build (small graph, single block) ----------------
__global__ void small_csr_kernel(const int* __restrict__ oei, int* __restrict__ rowptrS,
                                 int* __restrict__ srcsS) {
    __shared__ int sdeg[NS];
    __shared__ int scur[NS];
    int t = threadIdx.x;
    if (t < NS) sdeg[t] = 0;
    __syncthreads();
    for (int e = t; e < EO; e += 1024) atomicAdd(&sdeg[oei[EO + e]], 1);
    __syncthreads();
    int myv = (t < NS) ? sdeg[t] : 0;
    __syncthreads();
    for (int off = 1; off < NS; off <<= 1) {
        int x = (t >= off && t < NS) ? sdeg[t - off] : 0;
        __syncthreads();
        if (t < NS) sdeg[t] += x;
        __syncthreads();
    }
    if (t < NS) {
        int excl = sdeg[t] - myv;
        rowptrS[t] = excl;
        scur[t] = excl;
        if (t == 0) rowptrS[NS] = EO;
    }
    __syncthreads();
    for (int e = t; e < EO; e += 1024) {
        int d = oei[EO + e];
        int pos = atomicAdd(&scur[d], 1);
        srcsS[pos] = oei[e];
    }
}

// ---------------- per-subgraph fused gconv: LDS window + gather + MFMA ------
// One block = one subgraph. Window = transform(h1_prev) (or x at layer 0) held
// in LDS (128 KB); gather reads LDS (ds_read_b128) instead of global; combine
// is fused into the window load so h is never materialized. Root rows for the
// MFMA also come from the window. h1 read/written block-locally (no hazard).
// 1 block/CU (LDS-capped) -> VGPRs abundant, no spill (R7 lesson).
__global__ __launch_bounds__(512, 2) void gconv_sub_kernel(
    const float* __restrict__ hsrc,   // x (mode 0) or h1_prev (mode 1)
    const float* __restrict__ h2,     // raw small-gconv out, prev layer (mode 1)
    const float* __restrict__ stB, const float* __restrict__ stS,   // prev stats
    const float* __restrict__ gB, const float* __restrict__ bB,
    const float* __restrict__ gS, const float* __restrict__ bS,
    int mode,
    const int* __restrict__ rowptr, const unsigned short* __restrict__ ebuf,
    const float* __restrict__ Wr, const float* __restrict__ Wt,
    const float* __restrict__ br,
    float* __restrict__ hout, float* __restrict__ stats)
{
    extern __shared__ char smem[];
    float* Wn = (float*)smem;                              // 512*64 window
    float* agg = Wn + 512 * 64;                            // 64*68
    unsigned short* erec = (unsigned short*)(agg + 64 * 68); // RCAP
    float* bnp = (float*)(erec + RCAP);                    // 256

    int p = blockIdx.x;
    int sub = (p & 7) + 8 * (p >> 3);   // sub&7 == p&7: XCD-aligned with ebuf partition
    int tid = threadIdx.x;
    int w = tid >> 6;
    int l = tid & 63;

    // ---- BN params of previous layer (finalize fused) ----
    if (mode) {
        if (tid < 64) {
            int c = tid;
            float sb = 0.f, qb = 0.f, ss = 0.f, qs = 0.f;
            for (int r2 = 0; r2 < 32; r2++) {
                sb += stB[r2 * 128 + c];
                qb += stB[r2 * 128 + 64 + c];
                ss += stS[r2 * 128 + c];
                qs += stS[r2 * 128 + 64 + c];
            }
            float muB = sb * (1.f / 262144.f);
            float varB = qb * (1.f / 262144.f) - muB * muB;
            float scB = gB[c] * rsqrtf(varB + 1e-5f);
            bnp[c] = scB;
            bnp[64 + c] = bB[c] - muB * scB;
            float muS = ss * (1.f / 512.f);
            float varS = qs * (1.f / 512.f) - muS * muS;
            float scS = gS[c] * rsqrtf(varS + 1e-5f);
            bnp[128 + c] = scS;
            bnp[192 + c] = bS[c] - muS * scS;
        }
        __syncthreads();
    }

    // ---- window load (+ fused combine transform) ----
    const float* srcbase = hsrc + (size_t)sub * 512 * 64;
    for (int idx = tid; idx < 512 * 16; idx += 512) {
        int r = idx >> 4;
        int c4 = (idx & 15) * 4;
        float4 a = *(const float4*)(srcbase + r * 64 + c4);
        if (mode) {
            float4 b = *(const float4*)(h2 + r * 64 + c4);
            float4 sB4 = *(const float4*)(bnp + c4);
            float4 hB4 = *(const float4*)(bnp + 64 + c4);
            float4 sS4 = *(const float4*)(bnp + 128 + c4);
            float4 hS4 = *(const float4*)(bnp + 192 + c4);
            a.x = fmaxf(a.x * sB4.x + hB4.x + b.x * sS4.x + hS4.x, 0.f);
            a.y = fmaxf(a.y * sB4.y + hB4.y + b.y * sS4.y + hS4.y, 0.f);
            a.z = fmaxf(a.z * sB4.z + hB4.z + b.z * sS4.z + hS4.z, 0.f);
            a.w = fmaxf(a.w * sB4.w + hB4.w + b.w * sS4.w + hS4.w, 0.f);
        }
        *(float4*)(Wn + r * 64 + c4) = a;
    }

    // ---- B fragments (MFMA waves 0-3 only) ----
    int nt = w >> 1;
    int ct = w & 1;
    int n_out = ct * 32 + (l & 31);
    int kh = l >> 5;
    bf16x8 Bh[8], Bl[8];
    float bias = 0.f;
    if (w < 4) {
        #pragma unroll
        for (int kc = 0; kc < 8; kc++) {
            int kbase = kc * 16 + kh * 8;
            const float* wsrc = (kbase < 64) ? (Wr + n_out * 64 + kbase)
                                             : (Wt + n_out * 64 + (kbase - 64));
            float4 u0 = *(const float4*)(wsrc);
            float4 u1 = *(const float4*)(wsrc + 4);
            float vv[8] = {u0.x, u0.y, u0.z, u0.w, u1.x, u1.y, u1.z, u1.w};
            #pragma unroll
            for (int j = 0; j < 8; j++) {
                unsigned short hi = rne_bf16(vv[j]);
                float hif = __uint_as_float((unsigned int)hi << 16);
                Bh[kc][j] = (short)hi;
                Bl[kc][j] = (short)rne_bf16(vv[j] - hif);
            }
        }
        bias = br[n_out];
    }
    __syncthreads();   // window + bnp ready

    int qtr = l >> 4;
    int c4 = (l & 15) * 4;

    // ---- tile loop ----
    for (int tile = 0; tile < 8; tile++) {
        int nb = sub * 512 + tile * 64;
        int q0 = rowptr[nb], q1 = rowptr[nb + 64];
        int cnt = q1 - q0;
        if (cnt > RCAP) cnt = RCAP;   // statistically impossible; memory-safety
        for (int i = tid; i < cnt; i += 512) erec[i] = ebuf[q0 + i];
        __syncthreads();   // erec staged (also: prev MFMA done reading agg)

        // gather: wave owns rows [w*8, w*8+8); quarter owns 2 rows
        int r4 = w * 8 + qtr * 2;
        #pragma unroll
        for (int j = 0; j < 2; j++) {
            int row = r4 + j;
            int e0 = rowptr[nb + row] - q0;
            int e1 = rowptr[nb + row + 1] - q0;
            float4 accv = make_float4(0.f, 0.f, 0.f, 0.f);
            for (int pos = e0; pos < e1; pos += 4) {
                uint2 rr = *(const uint2*)(erec + pos);
                unsigned r0 = rr.x & 0xffffu, r1 = rr.x >> 16;
                unsigned r2 = rr.y & 0xffffu, r3 = rr.y >> 16;
                float m0 = (r0 != 0xffffu) ? 1.f : 0.f;
                float m1 = (r1 != 0xffffu) ? 1.f : 0.f;
                float m2 = (r2 != 0xffffu) ? 1.f : 0.f;
                float m3 = (r3 != 0xffffu) ? 1.f : 0.f;
                float4 v0 = *(const float4*)(Wn + (r0 & 511) * 64 + c4);
                float4 v1 = *(const float4*)(Wn + (r1 & 511) * 64 + c4);
                float4 v2 = *(const float4*)(Wn + (r2 & 511) * 64 + c4);
                float4 v3 = *(const float4*)(Wn + (r3 & 511) * 64 + c4);
                accv.x += v0.x * m0 + v1.x * m1 + v2.x * m2 + v3.x * m3;
                accv.y += v0.y * m0 + v1.y * m1 + v2.y * m2 + v3.y * m3;
                accv.z += v0.z * m0 + v1.z * m1 + v2.z * m2 + v3.z * m3;
                accv.w += v0.w * m0 + v1.w * m1 + v2.w * m2 + v3.w * m3;
            }
            *(float4*)(agg + row * 68 + c4) = accv;
        }
        __syncthreads();   // agg complete

        // MFMA + epilogue: waves 0-3
        if (w < 4) {
            f32x16 acc;
            #pragma unroll
            for (int j = 0; j < 16; j++) acc[j] = bias;
            int row = nt * 32 + (l & 31);
            const float* wrow = Wn + (tile * 64 + row) * 64;
            #pragma unroll
            for (int kc = 0; kc < 8; kc++) {
                int k0 = kc * 16 + kh * 8;
                float vv[8];
                if (kc < 4) {
                    float4 a0 = *(const float4*)(agg + row * 68 + k0);
                    float4 a1 = *(const float4*)(agg + row * 68 + k0 + 4);
                    vv[0]=a0.x; vv[1]=a0.y; vv[2]=a0.z; vv[3]=a0.w;
                    vv[4]=a1.x; vv[5]=a1.y; vv[6]=a1.z; vv[7]=a1.w;
                } else {
                    float4 a0 = *(const float4*)(wrow + k0 - 64);
                    float4 a1 = *(const float4*)(wrow + k0 - 60);
                    vv[0]=a0.x; vv[1]=a0.y; vv[2]=a0.z; vv[3]=a0.w;
                    vv[4]=a1.x; vv[5]=a1.y; vv[6]=a1.z; vv[7]=a1.w;
                }
                bf16x8 ah, al;
                #pragma unroll
                for (int j = 0; j < 8; j++) {
                    unsigned short hi = rne_bf16(vv[j]);
                    float hif = __uint_as_float((unsigned int)hi << 16);
                    ah[j] = (short)hi;
                    al[j] = (short)rne_bf16(vv[j] - hif);
                }
                acc = __builtin_amdgcn_mfma_f32_32x32x16_bf16(ah, Bh[kc], acc, 0, 0, 0);
                acc = __builtin_amdgcn_mfma_f32_32x32x16_bf16(al, Bh[kc], acc, 0, 0, 0);
                acc = __builtin_amdgcn_mfma_f32_32x32x16_bf16(ah, Bl[kc], acc, 0, 0, 0);
            }
            float s = 0.f, qv = 0.f;
            #pragma unroll
            for (int j = 0; j < 16; j++) {
                int crow = (j & 3) + 8 * (j >> 2) + 4 * (l >> 5);
                int node = nb + nt * 32 + crow;
                float v = acc[j];
                hout[node * 64 + n_out] = v;
                s += v;
                qv += v * v;
            }
            s += __shfl_xor(s, 32, 64);
            qv += __shfl_xor(qv, 32, 64);
            int rep = ((p << 3) | tile) & 31;
            if ((l & 32) == 0) {
                atomicAdd(&stats[rep * 128 + n_out], s);
                atomicAdd(&stats[rep * 128 + 64 + n_out], qv);
            }
        }
        __syncthreads();   // MFMA done reading agg/erec before next tile
    }
}

// ---------------- VALU gconv (512-node small graph) ----------
__global__ __launch_bounds__(512, 6) void gconv_kernel(
    const float* __restrict__ hin, const int* __restrict__ rowptr, const int* __restrict__ srcs,
    const float* __restrict__ Wr, const float* __restrict__ Wt, const float* __restrict__ br,
    float* __restrict__ hout, float* __restrict__ stats)
{
    __shared__ float wrt[4096];
    __shared__ float wtt[4096];
    __shared__ float4 aggT[8][64];
    __shared__ float4 hT[8][64];
    __shared__ float sbuf[8][64];
    __shared__ float qbuf[8][64];
    __shared__ float brs[64];

    int tid = threadIdx.x;
    for (int idx = tid; idx < 4096; idx += 512) {
        int cc = idx >> 6, kk = idx & 63;
        wrt[kk * 64 + ((kk + cc) & 63)] = Wr[idx];
        wtt[kk * 64 + ((kk + cc) & 63)] = Wt[idx];
    }
    if (tid < 64) brs[tid] = br[tid];
    __syncthreads();

    int w = tid >> 6;
    int c = tid & 63;
    int node0 = (blockIdx.x * 8 + w) * 4;

    float* aggp = (float*)&aggT[w][0];
    float* hp   = (float*)&hT[w][0];
    #pragma unroll
    for (int r = 0; r < 4; r++) {
        int node = node0 + r;
        hp[c * 4 + r] = hin[node * 64 + c];
        int e0 = rowptr[node], e1 = rowptr[node + 1];
        float a = 0.f;
        int e = e0;
        for (; e + 4 <= e1; e += 4) {
            int s0 = srcs[e], s1 = srcs[e + 1], s2 = srcs[e + 2], s3 = srcs[e + 3];
            float v0 = hin[s0 * 64 + c];
            float v1 = hin[s1 * 64 + c];
            float v2 = hin[s2 * 64 + c];
            float v3 = hin[s3 * 64 + c];
            a += (v0 + v1) + (v2 + v3);
        }
        for (; e < e1; e++) a += hin[srcs[e] * 64 + c];
        aggp[c * 4 + r] = a;
    }

    float o0 = brs[c], o1 = o0, o2 = o0, o3 = o0;
    #pragma unroll 8
    for (int k = 0; k < 64; k++) {
        float wr = wrt[k * 64 + ((k + c) & 63)];
        float wt = wtt[k * 64 + ((k + c) & 63)];
        float4 av = aggT[w][k];
        float4 hv = hT[w][k];
        o0 += wr * av.x + wt * hv.x;
        o1 += wr * av.y + wt * hv.y;
        o2 += wr * av.z + wt * hv.z;
        o3 += wr * av.w + wt * hv.w;
    }
    hout[(node0 + 0) * 64 + c] = o0;
    hout[(node0 + 1) * 64 + c] = o1;
    hout[(node0 + 2) * 64 + c] = o2;
    hout[(node0 + 3) * 64 + c] = o3;

    sbuf[w][c] = (o0 + o1) + (o2 + o3);
    qbuf[w][c] = (o0 * o0 + o1 * o1) + (o2 * o2 + o3 * o3);
    __syncthreads();
    int rep = blockIdx.x & 31;
    if (w == 0) {
        float s = 0.f;
        #pragma unroll
        for (int ww = 0; ww < 8; ww++) s += sbuf[ww][c];
        atomicAdd(&stats[rep * 128 + c], s);
    } else if (w == 1) {
        float q = 0.f;
        #pragma unroll
        for (int ww = 0; ww < 8; ww++) q += qbuf[ww][c];
        atomicAdd(&stats[rep * 128 + 64 + c], q);
    }
}

// ---- xsum[n] = smean over subgraphs of transform(h1) (or x at mode 0) ------
__global__ __launch_bounds__(1024) void xsum_kernel(
    const float* __restrict__ hsrc, const float* __restrict__ h2,
    const float* __restrict__ stB, const float* __restrict__ stS,
    const float* __restrict__ gB, const float* __restrict__ bB,
    const float* __restrict__ gS, const float* __restrict__ bS,
    int mode, float* __restrict__ xsum)
{
    __shared__ float bnp[256];
    __shared__ float red[16][64];
    int t = threadIdx.x;
    if (mode) {
        if (t < 64) {
            int c = t;
            float sb = 0.f, qb = 0.f, ss = 0.f, qs = 0.f;
            for (int r2 = 0; r2 < 32; r2++) {
                sb += stB[r2 * 128 + c];
                qb += stB[r2 * 128 + 64 + c];
                ss += stS[r2 * 128 + c];
                qs += stS[r2 * 128 + 64 + c];
            }
            float muB = sb * (1.f / 262144.f);
            float varB = qb * (1.f / 262144.f) - muB * muB;
            float scB = gB[c] * rsqrtf(varB + 1e-5f);
            bnp[c] = scB;
            bnp[64 + c] = bB[c] - muB * scB;
            float muS = ss * (1.f / 512.f);
            float varS = qs * (1.f / 512.f) - muS * muS;
            float scS = gS[c] * rsqrtf(varS + 1e-5f);
            bnp[128 + c] = scS;
            bnp[192 + c] = bS[c] - muS * scS;
        }
        __syncthreads();
    }

    int w = t >> 6;
    int l = t & 63;
    int c4 = (l & 15) * 4;
    int r = l >> 4;
    int n = blockIdx.x;

    float bx = 0.f, by = 0.f, bz = 0.f, bw = 0.f;
    float4 sB = make_float4(1.f, 1.f, 1.f, 1.f);
    float4 hB = make_float4(0.f, 0.f, 0.f, 0.f);
    if (mode) {
        sB = *(const float4*)(bnp + c4);
        hB = *(const float4*)(bnp + 64 + c4);
        float4 sS = *(const float4*)(bnp + 128 + c4);
        float4 hS = *(const float4*)(bnp + 192 + c4);
        float4 b2 = *(const float4*)(h2 + n * 64 + c4);
        bx = b2.x * sS.x + hS.x;
        by = b2.y * sS.y + hS.y;
        bz = b2.z * sS.z + hS.z;
        bw = b2.w * sS.w + hS.w;
    }

    float4 acc = make_float4(0.f, 0.f, 0.f, 0.f);
    #pragma unroll
    for (int j = 0; j < 8; j++) {
        int si = w * 32 + j * 4 + r;
        size_t base = (size_t)(si * 512 + n) * 64 + c4;
        float4 a = *(const float4*)(hsrc + base);
        float4 v;
        if (mode) {
            v.x = fmaxf(a.x * sB.x + hB.x + bx, 0.f);
            v.y = fmaxf(a.y * sB.y + hB.y + by, 0.f);
            v.z = fmaxf(a.z * sB.z + hB.z + bz, 0.f);
            v.w = fmaxf(a.w * sB.w + hB.w + bw, 0.f);
        } else {
            v = a;
        }
        acc.x += v.x; acc.y += v.y; acc.z += v.z; acc.w += v.w;
    }
    acc.x += __shfl_xor(acc.x, 16, 64); acc.y += __shfl_xor(acc.y, 16, 64);
    acc.z += __shfl_xor(acc.z, 16, 64); acc.w += __shfl_xor(acc.w, 16, 64);
    acc.x += __shfl_xor(acc.x, 32, 64); acc.y += __shfl_xor(acc.y, 32, 64);
    acc.z += __shfl_xor(acc.z, 32, 64); acc.w += __shfl_xor(acc.w, 32, 64);
    if (l < 16) {
        red[w][c4 + 0] = acc.x;
        red[w][c4 + 1] = acc.y;
        red[w][c4 + 2] = acc.z;
        red[w][c4 + 3] = acc.w;
    }
    __syncthreads();
    if (t < 64) {
        float tot = 0.f;
        #pragma unroll
        for (int ww = 0; ww < 16; ww++) tot += red[ww][t];
        xsum[n * 64 + t] = tot * (1.f / 512.f);
    }
}

// ---------------- head ----------------
__global__ void head_kernel(const float* __restrict__ xs, const float* __restrict__ W1,
                            const float* __restrict__ b1, const float* __restrict__ W2,
                            const float* __restrict__ b2, float* __restrict__ out) {
    __shared__ float z[64];
    __shared__ float hid[128];
    int t = threadIdx.x;
    int n = blockIdx.x;
    if (t < 64) {
        float v = xs[n * 64 + t];
        float m = v;
        for (int off = 32; off >= 1; off >>= 1) m = fmaxf(m, __shfl_xor(m, off, 64));
        float e = expf(v - m);
        float s = e;
        for (int off = 32; off >= 1; off >>= 1) s += __shfl_xor(s, off, 64);
        z[t] = v - m - logf(s);
    }
    __syncthreads();
    {
        float acc = b1[t];
        const float* wrow = W1 + t * 64;
        #pragma unroll 8
        for (int k = 0; k < 64; k++) acc += z[k] * wrow[k];
        hid[t] = fmaxf(acc, 0.f);
    }
    __syncthreads();
    if (t < 10) {
        float o = b2[t];
        const float* wrow = W2 + t * 128;
        #pragma unroll 8
        for (int j = 0; j < 128; j++) o += hid[j] * wrow[j];
        out[n * 10 + t] = o;
    }
}

extern "C" void kernel_launch(void* const* d_in, const int* in_sizes, int n_in,
                              void* d_out, int out_size, void* d_ws, size_t ws_size,
                              hipStream_t stream) {
    const float* x       = (const float*)d_in[0];
    const float* Wrel    = (const float*)d_in[1];
    const float* brel    = (const float*)d_in[2];
    const float* Wroot   = (const float*)d_in[3];
    const float* bn_g    = (const float*)d_in[4];
    const float* bn_b    = (const float*)d_in[5];
    const float* Wrel_s  = (const float*)d_in[6];
    const float* brel_s  = (const float*)d_in[7];
    const float* Wroot_s = (const float*)d_in[8];
    const float* bns_g   = (const float*)d_in[9];
    const float* bns_b   = (const float*)d_in[10];
    const float* W1      = (const float*)d_in[11];
    const float* b1      = (const float*)d_in[12];
    const float* W2      = (const float*)d_in[13];
    const float* b2      = (const float*)d_in[14];
    const int* ei        = (const int*)d_in[15];
    const int* oei       = (const int*)d_in[16];
    float* out = (float*)d_out;

    char* ws = (char*)d_ws;
    size_t off = 0;
    auto alloc = [&](size_t bytes) -> void* {
        void* p = ws + off;
        off = (off + bytes + 255) & ~(size_t)255;
        return p;
    };
    float* h1    = (float*)alloc((size_t)NT * 64 * 4);
    float* xsum  = (float*)alloc(NS * 64 * 4);
    float* h2    = (float*)alloc(NS * 64 * 4);
    float* stats = (float*)alloc(NLAYER * 2 * 4096 * 4);
    int* deg     = (int*)alloc((size_t)NT * 4);
    int* rowptr  = (int*)alloc((size_t)(NT + 1) * 4);
    int* cursor  = (int*)alloc((size_t)NT * 4);
    int* bsum    = (int*)alloc(256 * 4);
    unsigned short* ebuf = (unsigned short*)alloc((size_t)EP * 2);
    int* rowptrS = (int*)alloc(513 * 4);
    int* srcsS   = (int*)alloc(EO * 4);
    (void)ws_size; (void)in_sizes; (void)n_in; (void)out_size;

    hipMemsetAsync(deg, 0, (size_t)NT * 4, stream);
    hipMemsetAsync(stats, 0, (size_t)NLAYER * 2 * 4096 * 4, stream);
    hipMemsetAsync(ebuf, 0xFF, (size_t)EP * 2, stream);   // pad sentinel 0xFFFF

    hist_xcd_kernel<<<ES / EPB * 8, 256, 0, stream>>>(ei + ES, deg);
    scan1_kernel<<<NT / 1024, 1024, 0, stream>>>(deg, rowptr, bsum);
    scan2_kernel<<<1, 256, 0, stream>>>(bsum);
    scan3_kernel<<<NT / 1024, 1024, 0, stream>>>(rowptr, bsum, cursor, deg);
    scatter_xcd_kernel<<<ES / EPB * 8, 256, 0, stream>>>(ei, cursor, ebuf);
    small_csr_kernel<<<1, 1024, 0, stream>>>(oei, rowptrS, srcsS);

    const size_t SMEM = (512 * 64 + 64 * 68 + 256) * 4 + RCAP * 2;   // ~149.5 KB

    for (int i = 0; i < NLAYER; i++) {
        int mode = (i > 0);
        const float* hsrc = mode ? h1 : x;
        const float* stPB = stats + (i - 1) * 8192;        // prev layer stats
        const float* stPS = stPB + 4096;
        const float* gBp = bn_g + (i - 1) * 64;
        const float* bBp = bn_b + (i - 1) * 64;
        const float* gSp = bns_g + (i - 1) * 64;
        const float* bSp = bns_b + (i - 1) * 64;
        float* stB = stats + i * 8192;
        float* stS = stB + 4096;

        xsum_kernel<<<NS, 1024, 0, stream>>>(hsrc, h2, stPB, stPS, gBp, bBp, gSp, bSp,
                                             mode, xsum);
        gconv_sub_kernel<<<NS, 512, SMEM, stream>>>(hsrc, h2, stPB, stPS,
            gBp, bBp, gSp, bSp, mode, rowptr, ebuf,
            Wrel + i * 4096, Wroot + i * 4096, brel + i * 64, h1, stB);
        gconv_kernel<<<NS / 32, 512, 0, stream>>>(xsum, rowptrS, srcsS,
            Wrel_s + i * 4096, Wroot_s + i * 4096, brel_s + i * 64, h2, stS);
    }
    // final xsum = smean(h_final) from h1(3), stats(3)
    {
        const float* stPB = stats + 3 * 8192;
        const float* stPS = stPB + 4096;
        xsum_kernel<<<NS, 1024, 0, stream>>>(h1, h2, stPB, stPS,
            bn_g + 3 * 64, bn_b + 3 * 64, bns_g + 3 * 64, bns_b + 3 * 64, 1, xsum);
    }
    head_kernel<<<NS, 128, 0, stream>>>(xsum, W1, b1, W2, b2, out);
}